// Round 11
// baseline (215.827 us; speedup 1.0000x reference)
//
#include <hip/hip_runtime.h>
#include <hip/hip_bf16.h>
#include <math.h>

#define BATCH 8
#define SEQ   1024
#define DM    768
#define NHEAD 12
#define KVH   4
#define HD    64
#define REP   3

// softmax scale folded into Q weights, exp2 domain: 0.125 * log2(e)
#define QSCALE 0.18033688011112042f

typedef unsigned short u16;
typedef __attribute__((ext_vector_type(8))) __bf16 bf16x8;
typedef __attribute__((ext_vector_type(4))) float f32x4;
typedef __attribute__((ext_vector_type(4))) unsigned int u32x4;
typedef __attribute__((address_space(1))) const unsigned int gu32_c;
typedef __attribute__((address_space(3))) unsigned int su32;

// RTNE fp32 -> bf16 (finite values)
__device__ __forceinline__ u16 f2bf(float f) {
    unsigned int u = __float_as_uint(f);
    u += 0x7fffu + ((u >> 16) & 1u);
    return (u16)(u >> 16);
}

// ======== fused converts: x->bf16, Wqkv^T (Q cols pre-scaled), Wo^T ==========
__global__ __launch_bounds__(256) void cvt_all(
    const float* __restrict__ x,
    const float* __restrict__ qw, const float* __restrict__ kw,
    const float* __restrict__ vw, const float* __restrict__ ow,
    u16* __restrict__ xb, u16* __restrict__ wqkvt, u16* __restrict__ wot)
{
    const int NX = 8192 * DM / 4;          // float4 items
    const int NW = 1280 * DM;
    const int NO = DM * DM;
    const int i = blockIdx.x * 256 + threadIdx.x;
    if (i < NX) {
        const float4 v = ((const float4*)x)[i];
        ushort4 r;
        r.x = f2bf(v.x); r.y = f2bf(v.y); r.z = f2bf(v.z); r.w = f2bf(v.w);
        ((ushort4*)xb)[i] = r;
    } else if (i < NX + NW) {
        const int idx = i - NX;                // idx = n*768 + k
        const int k = idx % DM;
        const int n = idx / DM;
        float v;
        if (n < 768)       v = qw[(size_t)k * 768 + n] * QSCALE;
        else if (n < 1024) v = kw[(size_t)k * 256 + (n - 768)];
        else               v = vw[(size_t)k * 256 + (n - 1024)];
        wqkvt[idx] = f2bf(v);
    } else if (i < NX + NW + NO) {
        const int idx = i - NX - NW;
        const int k = idx % DM;
        const int n = idx / DM;
        wot[idx] = f2bf(ow[(size_t)k * DM + n]);
    }
}

// ======== 64x128-tile bf16 MFMA GEMM body: ring-4 counted-vmcnt pipeline ====
// Tile 64 (M) x 128 (N); 4 waves 2x2; wave = 32 rows x 64 cols; acc[2][4].
// STAGE = 3 global_load_lds (1 for A 64x32, 2 for B 128x32); prefetch 2 tiles
// ahead, s_waitcnt vmcnt(6) keeps the 2 future stages in flight, ONE raw
// s_barrier/iter.  WAR safety: slot (kt+2)&3 last read at compute(kt-2),
// finished before barrier kt-1 by every wave.
__device__ __forceinline__ void gemm64_body(
    const u16* __restrict__ A, const u16* __restrict__ B,
    int m0, int n0, u16 (*As)[2048], u16 (*Bs)[4096], f32x4 acc[2][4])
{
    const int tid  = threadIdx.x;
    const int lane = tid & 63;
    const int wid  = tid >> 6;
    const int wr = wid >> 1, wc = wid & 1;
    const int lo = lane & 15, hi = lane >> 4;

    const f32x4 z = {0.f, 0.f, 0.f, 0.f};
    #pragma unroll
    for (int i = 0; i < 2; i++)
        #pragma unroll
        for (int j = 0; j < 4; j++)
            acc[i][j] = z;

    const int NT = DM / 32;                   // 24 K-steps
    const int rowA = tid >> 2;
    const int colA = (tid & 3) << 3;

    #define STAGE_G(kt_, sl_) do {                                            \
        __builtin_amdgcn_global_load_lds(                                     \
            (gu32_c*)&A[(size_t)(m0 + rowA) * DM + (kt_) * 32 + colA],        \
            (su32*)&As[sl_][wid << 9], 16, 0, 0);                             \
        _Pragma("unroll")                                                     \
        for (int r_ = 0; r_ < 2; ++r_) {                                      \
            const int idx_  = r_ * 256 + tid;                                 \
            const int row_  = idx_ >> 2;                                      \
            const int col_  = (idx_ & 3) << 3;                                \
            const int base_ = (r_ * 256 + wid * 64) * 8;                      \
            __builtin_amdgcn_global_load_lds(                                 \
                (gu32_c*)&B[(size_t)(n0 + row_) * DM + (kt_) * 32 + col_],    \
                (su32*)&Bs[sl_][base_], 16, 0, 0);                            \
        }                                                                     \
    } while (0)

    STAGE_G(0, 0);
    STAGE_G(1, 1);

    for (int kt = 0; kt < NT; ++kt) {
        const int k2 = (kt + 2 < NT) ? kt + 2 : NT - 1;   // clamp: never read
        STAGE_G(k2, (kt + 2) & 3);
        asm volatile("s_waitcnt vmcnt(6)" ::: "memory");
        __builtin_amdgcn_s_barrier();
        __builtin_amdgcn_sched_barrier(0);

        const int sl = kt & 3;
        bf16x8 af[2], bfr[4];
        #pragma unroll
        for (int i = 0; i < 2; i++) af[i]  = *(const bf16x8*)&As[sl][(wr * 32 + i * 16 + lo) * 32 + hi * 8];
        #pragma unroll
        for (int j = 0; j < 4; j++) bfr[j] = *(const bf16x8*)&Bs[sl][(wc * 64 + j * 16 + lo) * 32 + hi * 8];
        #pragma unroll
        for (int i = 0; i < 2; i++)
            #pragma unroll
            for (int j = 0; j < 4; j++)
                acc[i][j] = __builtin_amdgcn_mfma_f32_16x16x32_bf16(af[i], bfr[j], acc[i][j], 0, 0, 0);
    }
    #undef STAGE_G
}

// ======== QKV projection -> Q/K [b,h,t,d]; V directly transposed [b,g,d,t] ==
// Grid 1280 = 8 XCD x 160 (exactly 5 blocks/CU: zero tail imbalance).
__global__ __launch_bounds__(256, 2) void gemm_qkv(
    const u16* __restrict__ xb, const u16* __restrict__ wt,
    const float* __restrict__ qb, const float* __restrict__ kb,
    const float* __restrict__ vb,
    u16* __restrict__ Q, u16* __restrict__ K, u16* __restrict__ Vt)
{
    __shared__ __align__(16) u16 As[4][2048];
    __shared__ __align__(16) u16 Bs[4][4096];
    const int id = (blockIdx.x & 7) * 160 + (blockIdx.x >> 3);
    const int m0 = (id / 10) * 64;
    const int n0 = (id % 10) * 128;
    f32x4 acc[2][4];
    gemm64_body(xb, wt, m0, n0, As, Bs, acc);

    const int tid = threadIdx.x;
    const int lane = tid & 63, wid = tid >> 6;
    const int wr = wid >> 1, wc = wid & 1;
    const int lo = lane & 15, hi = lane >> 4;

    #pragma unroll
    for (int j = 0; j < 4; j++) {
        const int n = n0 + wc * 64 + j * 16 + lo;
        if (n < 1024) {       // Q or K: [b,h,t,d] layout, scalar stores
            u16* outp; int nl, Hcnt; float bias;
            if (n < 768) { outp = Q; nl = n;       Hcnt = NHEAD; bias = qb[n] * QSCALE; }
            else         { outp = K; nl = n - 768; Hcnt = KVH;   bias = kb[nl]; }
            const int head = nl >> 6, d = nl & 63;
            #pragma unroll
            for (int i = 0; i < 2; i++) {
                #pragma unroll
                for (int r = 0; r < 4; r++) {
                    const int m = m0 + wr * 32 + i * 16 + hi * 4 + r;
                    const int b = m >> 10, t = m & 1023;
                    outp[(((size_t)(b * Hcnt + head)) * SEQ + t) * HD + d] =
                        f2bf(acc[i][j][r] + bias);
                }
            }
        } else {              // V: [b,g,d,t], ushort4 stores (4 consecutive t)
            const int nl = n - 1024;
            const float bias = vb[nl];
            const int head = nl >> 6, d = nl & 63;
            #pragma unroll
            for (int i = 0; i < 2; i++) {
                ushort4 vs;
                vs.x = f2bf(acc[i][j][0] + bias);
                vs.y = f2bf(acc[i][j][1] + bias);
                vs.z = f2bf(acc[i][j][2] + bias);
                vs.w = f2bf(acc[i][j][3] + bias);
                const int m = m0 + wr * 32 + i * 16 + hi * 4;
                const int b = m >> 10, t = m & 1023;
                *(ushort4*)&Vt[(((size_t)(b * KVH + head)) * HD + d) * SEQ + t] = vs;
            }
        }
    }
}

// ======== output projection: grid 768 = 8 XCD x 96 (exactly 3 blocks/CU) ====
__global__ __launch_bounds__(256, 2) void gemm_oproj(
    const u16* __restrict__ Ab, const u16* __restrict__ wt,
    const float* __restrict__ ob, float* __restrict__ outp)
{
    __shared__ __align__(16) u16 As[4][2048];
    __shared__ __align__(16) u16 Bs[4][4096];
    const int id = (blockIdx.x & 7) * 96 + (blockIdx.x >> 3);
    const int m0 = (id / 6) * 64;
    const int n0 = (id % 6) * 128;
    f32x4 acc[2][4];
    gemm64_body(Ab, wt, m0, n0, As, Bs, acc);

    const int tid = threadIdx.x;
    const int lane = tid & 63, wid = tid >> 6;
    const int wr = wid >> 1, wc = wid & 1;
    const int lo = lane & 15, hi = lane >> 4;

    #pragma unroll
    for (int j = 0; j < 4; j++) {
        const int n = n0 + wc * 64 + j * 16 + lo;
        const float bias = ob[n];
        #pragma unroll
        for (int i = 0; i < 2; i++) {
            #pragma unroll
            for (int r = 0; r < 4; r++) {
                const int m = m0 + wr * 32 + i * 16 + hi * 4 + r;
                outp[(size_t)m * DM + n] = acc[i][j][r] + bias;
            }
        }
    }
}

// ======== RoPE, Q and K fused in one launch (file-faithful interleave) ======
__global__ __launch_bounds__(256) void rope_naive(
    const __hip_bfloat16* __restrict__ Qin, __hip_bfloat16* __restrict__ Qout,
    const __hip_bfloat16* __restrict__ Kin, __hip_bfloat16* __restrict__ Kout,
    const int* __restrict__ pos)
{
    const long long qrows = (long long)BATCH * NHEAD * SEQ;   // 98304
    const long long krows = (long long)BATCH * KVH * SEQ;     // 32768
    const long long gid = (long long)blockIdx.x * 256 + threadIdx.x;
    if (gid >= (qrows + krows) * 64) return;
    long long row = gid >> 6;
    const int j = (int)(gid & 63);
    const __hip_bfloat16* in; __hip_bfloat16* outb;
    if (row < qrows) { in = Qin; outb = Qout; }
    else             { in = Kin; outb = Kout; row -= qrows; }
    const int t = (int)(row & (SEQ - 1));

    float p;
    if (pos[1] == 1)                              p = (float)pos[t];
    else if (((const float*)pos)[1] == 1.0f)      p = ((const float*)pos)[t];
    else                                          p = (float)pos[2 * t];

    const float inv = exp2f(-(float)(j & 31) * (13.287712379549449f / 32.0f));
    float sv, cv;
    sincosf(p * inv, &sv, &cv);
    const int partner = (j & 1) * 32 + (j >> 1) + ((j < 32) ? 16 : -16);
    const float sign  = (j < 32) ? -1.0f : 1.0f;
    const float val  = __bfloat162float(in[row * HD + j]);
    const float pv   = __bfloat162float(in[row * HD + partner]);
    outb[row * HD + j] = __float2bfloat16(val * cv + sign * pv * sv);
}

// ======== flash attention v9 (r10-best, FROZEN): row-split waves, LPT =======
__device__ __forceinline__ void strip_compute(
    const bf16x8& qf0, const bf16x8& qf1,
    const bf16x8& k0, const bf16x8& k1, const bf16x8& k2, const bf16x8& k3,
    const bf16x8* vv, bool diag, int msk0, int hi,
    float& m, float& l, f32x4* O)
{
    const f32x4 z = {0.f, 0.f, 0.f, 0.f};
    f32x4 a0 = z, a1 = z;
    __builtin_amdgcn_s_setprio(1);
    a0 = __builtin_amdgcn_mfma_f32_16x16x32_bf16(k0, qf0, a0, 0, 0, 0);
    a0 = __builtin_amdgcn_mfma_f32_16x16x32_bf16(k1, qf1, a0, 0, 0, 0);
    a1 = __builtin_amdgcn_mfma_f32_16x16x32_bf16(k2, qf0, a1, 0, 0, 0);
    a1 = __builtin_amdgcn_mfma_f32_16x16x32_bf16(k3, qf1, a1, 0, 0, 0);
    __builtin_amdgcn_s_setprio(0);

    float sc[8];
    #pragma unroll
    for (int e = 0; e < 8; ++e)
        sc[e] = (e < 4) ? a0[e & 3] : a1[e & 3];
    if (diag) {
        #pragma unroll
        for (int e = 0; e < 8; ++e) {
            const int srel = ((e >> 2) << 4) + (hi << 2) + (e & 3);
            if (srel > msk0) sc[e] = -3.0e38f;
        }
    }
    float pm = sc[0];
    #pragma unroll
    for (int e = 1; e < 8; ++e) pm = fmaxf(pm, sc[e]);

    if (!__all(pm - m <= 8.0f)) {            // defer-max (per-lane == per-row)
        float pr = fmaxf(pm, __shfl_xor(pm, 16));
        pr = fmaxf(pr, __shfl_xor(pr, 32));
        const float mn = fmaxf(m, pr);
        const float f = exp2f(m - mn);       // first tile: m=-3e38 -> f=0
        l *= f;
        #pragma unroll
        for (int r = 0; r < 4; ++r) {
            const float fr = __shfl(f, hi * 4 + r);
            #pragma unroll
            for (int dj = 0; dj < 4; ++dj) O[dj][r] *= fr;
        }
        m = mn;
    }

    union { u16 u[8]; bf16x8 v; } pu;
    float ps = 0.f;
    #pragma unroll
    for (int e = 0; e < 8; ++e) {
        const float p = exp2f(sc[e] - m);    // bounded by 2^8
        ps += p;
        pu.u[e] = f2bf(p);
    }
    l += ps;                                  // per-lane partial

    __builtin_amdgcn_s_setprio(1);
    #pragma unroll
    for (int dj = 0; dj < 4; ++dj)
        O[dj] = __builtin_amdgcn_mfma_f32_16x16x32_bf16(pu.v, vv[dj], O[dj], 0, 0, 0);
    __builtin_amdgcn_s_setprio(0);
}

__global__ __launch_bounds__(256, 4) void attn_mfma(
    const u16* __restrict__ Q, const u16* __restrict__ K,
    const u16* __restrict__ Vt, u16* __restrict__ outp)
{
    __shared__ __align__(16) u16 Ks[4][2048];   // ring-4: 32 s x 64 d, swizzled
    __shared__ __align__(16) u16 Vs[4][2048];   // ring-4: 64 d x 32 s, permuted

    const int blk = blockIdx.x;                  // 1536 = 8b*12h*16a
    const int xcd = blk & 7;
    const int jj  = blk >> 3;                    // 0..191
    const int bg  = (xcd << 2) + (jj & 3);       // 0..31
    const int rh  = jj >> 2;                     // 0..47
    const int a   = 15 - rh / 3;                 // q-block, DESCENDING (LPT)
    const int hl  = rh % 3;
    const int b   = bg >> 2, g = bg & 3;
    const int h   = g * REP + hl;

    const int wid  = threadIdx.x >> 6;
    const int lane = threadIdx.x & 63;
    const int lo = lane & 15, hi = lane >> 4;

    const int w    = (a << 2) + wid;             // strip 0..63 (16 q-rows)
    const int q0   = w << 4;
    const int dT   = w >> 1;                     // last tile for this strip
    const int msk0 = lo + ((w & 1) << 4);
    const int nstT = (a << 1) + 2;               // block trip count (= max dT+1)

    const u16* Kp = K  + (size_t)(b * KVH + g) * SEQ * HD;
    const u16* Vp = Vt + (size_t)(b * KVH + g) * SEQ * HD;   // [d][s]

    const int jK = (wid << 6) + lane;
    const int sKoff = (jK ^ ((jK >> 3) & 7)) << 3;           // u16 offset
    int vsoff[4];
    #pragma unroll
    for (int q = 0; q < 4; ++q) {
        const int dw  = (wid << 8) + (q << 6) + lane;
        const int R   = dw >> 4;
        const int wd  = dw & 15;
        const int hpl = (wd >> 2) ^ ((R >> 1) & 3);
        vsoff[q] = (R << 10) + (hpl << 2) + (((wd >> 1) & 1) << 4) + ((wd & 1) << 1);
    }

    const u16* Qp = Q + ((size_t)(b * NHEAD + h) * SEQ + q0) * HD;
    const bf16x8 qf0 = *(const bf16x8*)&Qp[(size_t)lo * HD + hi * 8];
    const bf16x8 qf1 = *(const bf16x8*)&Qp[(size_t)lo * HD + 32 + hi * 8];

    const f32x4 z = {0.f, 0.f, 0.f, 0.f};
    f32x4 O[4];
    #pragma unroll
    for (int dj = 0; dj < 4; ++dj) O[dj] = z;
    float m = -3.0e38f, l = 0.f;

    #define STAGE(st_, sl_) do {                                              \
        const int s0_ = (st_) << 5;                                           \
        __builtin_amdgcn_global_load_lds(                                     \
            (gu32_c*)(Kp + (s0_ << 6) + sKoff),                               \
            (su32*)&Ks[sl_][wid << 9], 16, 0, 0);                             \
        _Pragma("unroll")                                                     \
        for (int q_ = 0; q_ < 4; ++q_)                                        \
            __builtin_amdgcn_global_load_lds(                                 \
                (gu32_c*)(Vp + s0_ + vsoff[q_]),                              \
                (su32*)&Vs[sl_][(wid << 9) + (q_ << 7)], 4, 0, 0);            \
    } while (0)

    STAGE(0, 0);
    STAGE(1, 1);

    const int xorK = lo & 7;
    for (int st = 0; st < nstT; ++st) {
        const int s2 = (st + 2 < nstT) ? st + 2 : nstT - 1;  // clamp: never read
        STAGE(s2, (st + 2) & 3);
        asm volatile("s_waitcnt vmcnt(10)" ::: "memory");
        __builtin_amdgcn_s_barrier();
        __builtin_amdgcn_sched_barrier(0);

        if (st <= dT) {
            const int sl = st & 3;
            const u16* kb_ = Ks[sl];
            const bf16x8 k0 = *(const bf16x8*)&kb_[((lo << 3) + (hi ^ xorK)) << 3];
            const bf16x8 k1 = *(const bf16x8*)&kb_[((lo << 3) + ((4 + hi) ^ xorK)) << 3];
            const bf16x8 k2 = *(const bf16x8*)&kb_[(((16 + lo) << 3) + (hi ^ xorK)) << 3];
            const bf16x8 k3 = *(const bf16x8*)&kb_[(((16 + lo) << 3) + ((4 + hi) ^ xorK)) << 3];
            bf16x8 vv[4];
            #pragma unroll
            for (int dj = 0; dj < 4; ++dj) {
                const int R = dj * 16 + lo;
                vv[dj] = *(const bf16x8*)&Vs[sl][(R << 5) + ((hi ^ ((R >> 1) & 3)) << 3)];
            }
            strip_compute(qf0, qf1, k0, k1, k2, k3, vv, st == dT, msk0, hi, m, l, O);
        }
    }
    #undef STAGE

    // epilogue: reduce per-lane l across hi-groups, then per-row store
    l += __shfl_xor(l, 16); l += __shfl_xor(l, 32);
    #pragma unroll
    for (int r = 0; r < 4; ++r) {
        const float li = 1.0f / fmaxf(__shfl(l, hi * 4 + r), 1e-37f);
        const int t = q0 + hi * 4 + r;
        #pragma unroll
        for (int dj = 0; dj < 4; ++dj)
            outp[((size_t)(b * SEQ + t)) * DM + h * HD + dj * 16 + lo] = f2bf(O[dj][r] * li);
    }
}

extern "C" void kernel_launch(void* const* d_in, const int* in_sizes, int n_in,
                              void* d_out, int out_size, void* d_ws, size_t ws_size,
                              hipStream_t stream) {
    const float* x   = (const float*)d_in[0];
    const int*   pos = (const int*)d_in[1];
    const float* qw  = (const float*)d_in[2];
    const float* qb  = (const float*)d_in[3];
    const float* kw  = (const float*)d_in[4];
    const float* kb  = (const float*)d_in[5];
    const float* vw  = (const float*)d_in[6];
    const float* vb  = (const float*)d_in[7];
    const float* ow  = (const float*)d_in[8];
    const float* ob  = (const float*)d_in[9];
    float* out = (float*)d_out;                 // OUTPUT IS FP32

    u16* xb    = (u16*)d_ws;                                    // 6291456
    u16* Wqkvt = xb    + (size_t)8192 * DM;                     //  983040
    u16* Wot   = Wqkvt + (size_t)1280 * DM;                     //  589824
    u16* Qbuf  = Wot   + (size_t)DM * DM;                       // 6291456
    u16* Kbuf  = Qbuf  + (size_t)BATCH * NHEAD * SEQ * HD;      // 2097152
    u16* Krot  = Kbuf  + (size_t)BATCH * KVH * SEQ * HD;        // 2097152
    u16* Vtb   = Krot  + (size_t)BATCH * KVH * SEQ * HD;        // 2097152 [b,g,d,s]
    u16* Qrot  = xb;     // alias: xb dead after gemm_qkv
    u16* attn  = Qbuf;   // alias: Qbuf dead after rope

    const int NCVT = 8192 * DM / 4 + 1280 * DM + DM * DM;
    cvt_all<<<(NCVT + 255) / 256, 256, 0, stream>>>(x, qw, kw, vw, ow, xb, Wqkvt, Wot);

    gemm_qkv<<<1280, 256, 0, stream>>>(xb, Wqkvt, qb, kb, vb, Qbuf, Kbuf, Vtb);

    const long long allrows = (long long)BATCH * (NHEAD + KVH) * SEQ;  // 131072
    rope_naive<<<(int)((allrows * 64 + 255) / 256), 256, 0, stream>>>(
        (const __hip_bfloat16*)Qbuf, (__hip_bfloat16*)Qrot,
        (const __hip_bfloat16*)Kbuf, (__hip_bfloat16*)Krot, pos);

    attn_mfma<<<1536, 256, 0, stream>>>(Qrot, Krot, Vtb, attn);

    gemm_oproj<<<768, 256, 0, stream>>>(attn, Wot, ob, out);
}

// Round 12
// 196.307 us; speedup vs baseline: 1.0994x; 1.0994x over previous
//
#include <hip/hip_runtime.h>
#include <hip/hip_bf16.h>
#include <math.h>

#define BATCH 8
#define SEQ   1024
#define DM    768
#define NHEAD 12
#define KVH   4
#define HD    64
#define REP   3

// softmax scale folded into Q weights, exp2 domain: 0.125 * log2(e)
#define QSCALE 0.18033688011112042f
// RoPE: inv_freq(j) = exp2(-j * LOG2_BASE_OVER_HALF / 32), j in [0,32)
#define ROPE_C (13.287712379549449f / 32.0f)

typedef unsigned short u16;
typedef __attribute__((ext_vector_type(8))) __bf16 bf16x8;
typedef __attribute__((ext_vector_type(4))) float f32x4;
typedef __attribute__((ext_vector_type(4))) unsigned int u32x4;
typedef __attribute__((address_space(1))) const unsigned int gu32_c;
typedef __attribute__((address_space(3))) unsigned int su32;

// RTNE fp32 -> bf16 (finite values)
__device__ __forceinline__ u16 f2bf(float f) {
    unsigned int u = __float_as_uint(f);
    u += 0x7fffu + ((u >> 16) & 1u);
    return (u16)(u >> 16);
}

// ======== fused converts: x->bf16, Wqkv^T (Q cols pre-scaled), Wo^T ==========
__global__ __launch_bounds__(256) void cvt_all(
    const float* __restrict__ x,
    const float* __restrict__ qw, const float* __restrict__ kw,
    const float* __restrict__ vw, const float* __restrict__ ow,
    u16* __restrict__ xb, u16* __restrict__ wqkvt, u16* __restrict__ wot)
{
    const int NX = 8192 * DM / 4;          // float4 items
    const int NW = 1280 * DM;
    const int NO = DM * DM;
    const int i = blockIdx.x * 256 + threadIdx.x;
    if (i < NX) {
        const float4 v = ((const float4*)x)[i];
        ushort4 r;
        r.x = f2bf(v.x); r.y = f2bf(v.y); r.z = f2bf(v.z); r.w = f2bf(v.w);
        ((ushort4*)xb)[i] = r;
    } else if (i < NX + NW) {
        const int idx = i - NX;                // idx = n*768 + k
        const int k = idx % DM;
        const int n = idx / DM;
        float v;
        if (n < 768)       v = qw[(size_t)k * 768 + n] * QSCALE;
        else if (n < 1024) v = kw[(size_t)k * 256 + (n - 768)];
        else               v = vw[(size_t)k * 256 + (n - 1024)];
        wqkvt[idx] = f2bf(v);
    } else if (i < NX + NW + NO) {
        const int idx = i - NX - NW;
        const int k = idx % DM;
        const int n = idx / DM;
        wot[idx] = f2bf(ow[(size_t)k * DM + n]);
    }
}

// ======== 64x128-tile bf16 MFMA GEMM body: ring-4 counted-vmcnt pipeline ====
__device__ __forceinline__ void gemm64_body(
    const u16* __restrict__ A, const u16* __restrict__ B,
    int m0, int n0, u16 (*As)[2048], u16 (*Bs)[4096], f32x4 acc[2][4])
{
    const int tid  = threadIdx.x;
    const int lane = tid & 63;
    const int wid  = tid >> 6;
    const int wr = wid >> 1, wc = wid & 1;
    const int lo = lane & 15, hi = lane >> 4;

    const f32x4 z = {0.f, 0.f, 0.f, 0.f};
    #pragma unroll
    for (int i = 0; i < 2; i++)
        #pragma unroll
        for (int j = 0; j < 4; j++)
            acc[i][j] = z;

    const int NT = DM / 32;                   // 24 K-steps
    const int rowA = tid >> 2;
    const int colA = (tid & 3) << 3;

    #define STAGE_G(kt_, sl_) do {                                            \
        __builtin_amdgcn_global_load_lds(                                     \
            (gu32_c*)&A[(size_t)(m0 + rowA) * DM + (kt_) * 32 + colA],        \
            (su32*)&As[sl_][wid << 9], 16, 0, 0);                             \
        _Pragma("unroll")                                                     \
        for (int r_ = 0; r_ < 2; ++r_) {                                      \
            const int idx_  = r_ * 256 + tid;                                 \
            const int row_  = idx_ >> 2;                                      \
            const int col_  = (idx_ & 3) << 3;                                \
            const int base_ = (r_ * 256 + wid * 64) * 8;                      \
            __builtin_amdgcn_global_load_lds(                                 \
                (gu32_c*)&B[(size_t)(n0 + row_) * DM + (kt_) * 32 + col_],    \
                (su32*)&Bs[sl_][base_], 16, 0, 0);                            \
        }                                                                     \
    } while (0)

    STAGE_G(0, 0);
    STAGE_G(1, 1);

    for (int kt = 0; kt < NT; ++kt) {
        const int k2 = (kt + 2 < NT) ? kt + 2 : NT - 1;   // clamp: never read
        STAGE_G(k2, (kt + 2) & 3);
        asm volatile("s_waitcnt vmcnt(6)" ::: "memory");
        __builtin_amdgcn_s_barrier();
        __builtin_amdgcn_sched_barrier(0);

        const int sl = kt & 3;
        bf16x8 af[2], bfr[4];
        #pragma unroll
        for (int i = 0; i < 2; i++) af[i]  = *(const bf16x8*)&As[sl][(wr * 32 + i * 16 + lo) * 32 + hi * 8];
        #pragma unroll
        for (int j = 0; j < 4; j++) bfr[j] = *(const bf16x8*)&Bs[sl][(wc * 64 + j * 16 + lo) * 32 + hi * 8];
        #pragma unroll
        for (int i = 0; i < 2; i++)
            #pragma unroll
            for (int j = 0; j < 4; j++)
                acc[i][j] = __builtin_amdgcn_mfma_f32_16x16x32_bf16(af[i], bfr[j], acc[i][j], 0, 0, 0);
    }
    #undef STAGE_G
}

// ======== QKV projection with FUSED RoPE ====================================
// Per wave, segment seg = n0 + wc*64 is 64-aligned -> wholly Q, K or V, ONE
// head; thread holds d = {lo, lo+16, lo+32, lo+48} of rows shared by its
// hi-group.  RoPE partner(d) = (d&1)*32 + (d>>1) +- 16 lives at lane
// (hi<<4) | ((j&1)*8 + (lo>>1)), slot jp in {1,3} (j<2) or {0,2} (j>=2) by
// lo parity -> 8 __shfl per row.  Angles: d&31 in {lo, 16+lo} -> 2 sincos/row.
// Q rope'd on pre-scaled values (rope linear, scale commutes).  V stored
// transposed [b,g,d,t].  Grid 1280 = 8 XCD x 160 (5 blocks/CU exact).
__global__ __launch_bounds__(256, 2) void gemm_qkv(
    const u16* __restrict__ xb, const u16* __restrict__ wt,
    const float* __restrict__ qb, const float* __restrict__ kb,
    const float* __restrict__ vb, const int* __restrict__ pos,
    u16* __restrict__ Q, u16* __restrict__ K, u16* __restrict__ Vt)
{
    __shared__ __align__(16) u16 As[4][2048];
    __shared__ __align__(16) u16 Bs[4][4096];
    const int id = (blockIdx.x & 7) * 160 + (blockIdx.x >> 3);
    const int m0 = (id / 10) * 64;
    const int n0 = (id % 10) * 128;
    f32x4 acc[2][4];
    gemm64_body(xb, wt, m0, n0, As, Bs, acc);

    const int tid = threadIdx.x;
    const int lane = tid & 63, wid = tid >> 6;
    const int wr = wid >> 1, wc = wid & 1;
    const int lo = lane & 15, hi = lane >> 4;

    const int seg = n0 + wc * 64;            // wave-uniform, 64-aligned

    if (seg >= 1024) {
        // V: [b,g,d,t], ushort4 stores (4 consecutive t)
        #pragma unroll
        for (int j = 0; j < 4; j++) {
            const int nl = seg - 1024 + j * 16 + lo;
            const float bias = vb[nl];
            const int head = nl >> 6, d = nl & 63;
            #pragma unroll
            for (int i = 0; i < 2; i++) {
                ushort4 vs;
                vs.x = f2bf(acc[i][j][0] + bias);
                vs.y = f2bf(acc[i][j][1] + bias);
                vs.z = f2bf(acc[i][j][2] + bias);
                vs.w = f2bf(acc[i][j][3] + bias);
                const int m = m0 + wr * 32 + i * 16 + hi * 4;
                const int b = m >> 10, t = m & 1023;
                *(ushort4*)&Vt[(((size_t)(b * KVH + head)) * HD + d) * SEQ + t] = vs;
            }
        }
    } else {
        const bool isQ = seg < 768;
        const int  segl = isQ ? seg : seg - 768;
        const int  head = segl >> 6;
        const int  Hcnt = isQ ? NHEAD : KVH;
        u16* outp = isQ ? Q : K;
        float bias[4];
        #pragma unroll
        for (int j = 0; j < 4; j++) {
            const int nl = segl + j * 16 + lo;
            bias[j] = isQ ? qb[nl] * QSCALE : kb[nl];
        }
        // rope constants (per lane)
        const float inv0 = exp2f(-(float)lo * ROPE_C);
        const float inv1 = exp2f(-(float)(16 + lo) * ROPE_C);
        int pmode;                             // pos dtype robustness
        if (pos[1] == 1)                         pmode = 0;
        else if (((const float*)pos)[1] == 1.0f) pmode = 1;
        else                                     pmode = 2;
        const int src0 = (hi << 4) | (lo >> 1);
        const int src1 = src0 | 8;
        const bool odd = (lo & 1) != 0;

        #pragma unroll
        for (int i = 0; i < 2; i++) {
            #pragma unroll
            for (int r = 0; r < 4; r++) {
                const float v0 = acc[i][0][r] + bias[0];
                const float v1 = acc[i][1][r] + bias[1];
                const float v2 = acc[i][2][r] + bias[2];
                const float v3 = acc[i][3][r] + bias[3];
                // partner values (raw) via hi-group shuffles
                const float p0e = __shfl(v1, src0), p0o = __shfl(v3, src0);
                const float p1e = __shfl(v1, src1), p1o = __shfl(v3, src1);
                const float p2e = __shfl(v0, src0), p2o = __shfl(v2, src0);
                const float p3e = __shfl(v0, src1), p3o = __shfl(v2, src1);
                const float px0 = odd ? p0o : p0e;
                const float px1 = odd ? p1o : p1e;
                const float px2 = odd ? p2o : p2e;
                const float px3 = odd ? p3o : p3e;

                const int m = m0 + wr * 32 + i * 16 + hi * 4 + r;
                const int b = m >> 10, t = m & 1023;
                float pp;
                if (pmode == 0)      pp = (float)pos[t];
                else if (pmode == 1) pp = ((const float*)pos)[t];
                else                 pp = (float)pos[2 * t];

                float sv0, cv0, sv1, cv1;
                sincosf(pp * inv0, &sv0, &cv0);
                sincosf(pp * inv1, &sv1, &cv1);
                // d = lo, 16+lo: sign -, th = inv0, inv1; d = 32+lo, 48+lo: sign +
                const float o0 = v0 * cv0 - px0 * sv0;
                const float o1 = v1 * cv1 - px1 * sv1;
                const float o2 = v2 * cv0 + px2 * sv0;
                const float o3 = v3 * cv1 + px3 * sv1;

                u16* dst = outp + ((size_t)(b * Hcnt + head) * SEQ + t) * HD;
                dst[lo]      = f2bf(o0);
                dst[16 + lo] = f2bf(o1);
                dst[32 + lo] = f2bf(o2);
                dst[48 + lo] = f2bf(o3);
            }
        }
    }
}

// ======== output projection: grid 768 = 8 XCD x 96 (exactly 3 blocks/CU) ====
__global__ __launch_bounds__(256, 2) void gemm_oproj(
    const u16* __restrict__ Ab, const u16* __restrict__ wt,
    const float* __restrict__ ob, float* __restrict__ outp)
{
    __shared__ __align__(16) u16 As[4][2048];
    __shared__ __align__(16) u16 Bs[4][4096];
    const int id = (blockIdx.x & 7) * 96 + (blockIdx.x >> 3);
    const int m0 = (id / 6) * 64;
    const int n0 = (id % 6) * 128;
    f32x4 acc[2][4];
    gemm64_body(Ab, wt, m0, n0, As, Bs, acc);

    const int tid = threadIdx.x;
    const int lane = tid & 63, wid = tid >> 6;
    const int wr = wid >> 1, wc = wid & 1;
    const int lo = lane & 15, hi = lane >> 4;

    #pragma unroll
    for (int j = 0; j < 4; j++) {
        const int n = n0 + wc * 64 + j * 16 + lo;
        const float bias = ob[n];
        #pragma unroll
        for (int i = 0; i < 2; i++) {
            #pragma unroll
            for (int r = 0; r < 4; r++) {
                const int m = m0 + wr * 32 + i * 16 + hi * 4 + r;
                outp[(size_t)m * DM + n] = acc[i][j][r] + bias;
            }
        }
    }
}

// ======== flash attention v9 (FROZEN, r10-best): row-split waves, LPT =======
__device__ __forceinline__ void strip_compute(
    const bf16x8& qf0, const bf16x8& qf1,
    const bf16x8& k0, const bf16x8& k1, const bf16x8& k2, const bf16x8& k3,
    const bf16x8* vv, bool diag, int msk0, int hi,
    float& m, float& l, f32x4* O)
{
    const f32x4 z = {0.f, 0.f, 0.f, 0.f};
    f32x4 a0 = z, a1 = z;
    __builtin_amdgcn_s_setprio(1);
    a0 = __builtin_amdgcn_mfma_f32_16x16x32_bf16(k0, qf0, a0, 0, 0, 0);
    a0 = __builtin_amdgcn_mfma_f32_16x16x32_bf16(k1, qf1, a0, 0, 0, 0);
    a1 = __builtin_amdgcn_mfma_f32_16x16x32_bf16(k2, qf0, a1, 0, 0, 0);
    a1 = __builtin_amdgcn_mfma_f32_16x16x32_bf16(k3, qf1, a1, 0, 0, 0);
    __builtin_amdgcn_s_setprio(0);

    float sc[8];
    #pragma unroll
    for (int e = 0; e < 8; ++e)
        sc[e] = (e < 4) ? a0[e & 3] : a1[e & 3];
    if (diag) {
        #pragma unroll
        for (int e = 0; e < 8; ++e) {
            const int srel = ((e >> 2) << 4) + (hi << 2) + (e & 3);
            if (srel > msk0) sc[e] = -3.0e38f;
        }
    }
    float pm = sc[0];
    #pragma unroll
    for (int e = 1; e < 8; ++e) pm = fmaxf(pm, sc[e]);

    if (!__all(pm - m <= 8.0f)) {            // defer-max (per-lane == per-row)
        float pr = fmaxf(pm, __shfl_xor(pm, 16));
        pr = fmaxf(pr, __shfl_xor(pr, 32));
        const float mn = fmaxf(m, pr);
        const float f = exp2f(m - mn);       // first tile: m=-3e38 -> f=0
        l *= f;
        #pragma unroll
        for (int r = 0; r < 4; ++r) {
            const float fr = __shfl(f, hi * 4 + r);
            #pragma unroll
            for (int dj = 0; dj < 4; ++dj) O[dj][r] *= fr;
        }
        m = mn;
    }

    union { u16 u[8]; bf16x8 v; } pu;
    float ps = 0.f;
    #pragma unroll
    for (int e = 0; e < 8; ++e) {
        const float p = exp2f(sc[e] - m);    // bounded by 2^8
        ps += p;
        pu.u[e] = f2bf(p);
    }
    l += ps;                                  // per-lane partial

    __builtin_amdgcn_s_setprio(1);
    #pragma unroll
    for (int dj = 0; dj < 4; ++dj)
        O[dj] = __builtin_amdgcn_mfma_f32_16x16x32_bf16(pu.v, vv[dj], O[dj], 0, 0, 0);
    __builtin_amdgcn_s_setprio(0);
}

__global__ __launch_bounds__(256, 4) void attn_mfma(
    const u16* __restrict__ Q, const u16* __restrict__ K,
    const u16* __restrict__ Vt, u16* __restrict__ outp)
{
    __shared__ __align__(16) u16 Ks[4][2048];   // ring-4: 32 s x 64 d, swizzled
    __shared__ __align__(16) u16 Vs[4][2048];   // ring-4: 64 d x 32 s, permuted

    const int blk = blockIdx.x;                  // 1536 = 8b*12h*16a
    const int xcd = blk & 7;
    const int jj  = blk >> 3;                    // 0..191
    const int bg  = (xcd << 2) + (jj & 3);       // 0..31
    const int rh  = jj >> 2;                     // 0..47
    const int a   = 15 - rh / 3;                 // q-block, DESCENDING (LPT)
    const int hl  = rh % 3;
    const int b   = bg >> 2, g = bg & 3;
    const int h   = g * REP + hl;

    const int wid  = threadIdx.x >> 6;
    const int lane = threadIdx.x & 63;
    const int lo = lane & 15, hi = lane >> 4;

    const int w    = (a << 2) + wid;             // strip 0..63 (16 q-rows)
    const int q0   = w << 4;
    const int dT   = w >> 1;                     // last tile for this strip
    const int msk0 = lo + ((w & 1) << 4);
    const int nstT = (a << 1) + 2;               // block trip count (= max dT+1)

    const u16* Kp = K  + (size_t)(b * KVH + g) * SEQ * HD;
    const u16* Vp = Vt + (size_t)(b * KVH + g) * SEQ * HD;   // [d][s]

    const int jK = (wid << 6) + lane;
    const int sKoff = (jK ^ ((jK >> 3) & 7)) << 3;           // u16 offset
    int vsoff[4];
    #pragma unroll
    for (int q = 0; q < 4; ++q) {
        const int dw  = (wid << 8) + (q << 6) + lane;
        const int R   = dw >> 4;
        const int wd  = dw & 15;
        const int hpl = (wd >> 2) ^ ((R >> 1) & 3);
        vsoff[q] = (R << 10) + (hpl << 2) + (((wd >> 1) & 1) << 4) + ((wd & 1) << 1);
    }

    const u16* Qp = Q + ((size_t)(b * NHEAD + h) * SEQ + q0) * HD;
    const bf16x8 qf0 = *(const bf16x8*)&Qp[(size_t)lo * HD + hi * 8];
    const bf16x8 qf1 = *(const bf16x8*)&Qp[(size_t)lo * HD + 32 + hi * 8];

    const f32x4 z = {0.f, 0.f, 0.f, 0.f};
    f32x4 O[4];
    #pragma unroll
    for (int dj = 0; dj < 4; ++dj) O[dj] = z;
    float m = -3.0e38f, l = 0.f;

    #define STAGE(st_, sl_) do {                                              \
        const int s0_ = (st_) << 5;                                           \
        __builtin_amdgcn_global_load_lds(                                     \
            (gu32_c*)(Kp + (s0_ << 6) + sKoff),                               \
            (su32*)&Ks[sl_][wid << 9], 16, 0, 0);                             \
        _Pragma("unroll")                                                     \
        for (int q_ = 0; q_ < 4; ++q_)                                        \
            __builtin_amdgcn_global_load_lds(                                 \
                (gu32_c*)(Vp + s0_ + vsoff[q_]),                              \
                (su32*)&Vs[sl_][(wid << 9) + (q_ << 7)], 4, 0, 0);            \
    } while (0)

    STAGE(0, 0);
    STAGE(1, 1);

    const int xorK = lo & 7;
    for (int st = 0; st < nstT; ++st) {
        const int s2 = (st + 2 < nstT) ? st + 2 : nstT - 1;  // clamp: never read
        STAGE(s2, (st + 2) & 3);
        asm volatile("s_waitcnt vmcnt(10)" ::: "memory");
        __builtin_amdgcn_s_barrier();
        __builtin_amdgcn_sched_barrier(0);

        if (st <= dT) {
            const int sl = st & 3;
            const u16* kb_ = Ks[sl];
            const bf16x8 k0 = *(const bf16x8*)&kb_[((lo << 3) + (hi ^ xorK)) << 3];
            const bf16x8 k1 = *(const bf16x8*)&kb_[((lo << 3) + ((4 + hi) ^ xorK)) << 3];
            const bf16x8 k2 = *(const bf16x8*)&kb_[(((16 + lo) << 3) + (hi ^ xorK)) << 3];
            const bf16x8 k3 = *(const bf16x8*)&kb_[(((16 + lo) << 3) + ((4 + hi) ^ xorK)) << 3];
            bf16x8 vv[4];
            #pragma unroll
            for (int dj = 0; dj < 4; ++dj) {
                const int R = dj * 16 + lo;
                vv[dj] = *(const bf16x8*)&Vs[sl][(R << 5) + ((hi ^ ((R >> 1) & 3)) << 3)];
            }
            strip_compute(qf0, qf1, k0, k1, k2, k3, vv, st == dT, msk0, hi, m, l, O);
        }
    }
    #undef STAGE

    // epilogue: reduce per-lane l across hi-groups, then per-row store
    l += __shfl_xor(l, 16); l += __shfl_xor(l, 32);
    #pragma unroll
    for (int r = 0; r < 4; ++r) {
        const float li = 1.0f / fmaxf(__shfl(l, hi * 4 + r), 1e-37f);
        const int t = q0 + hi * 4 + r;
        #pragma unroll
        for (int dj = 0; dj < 4; ++dj)
            outp[((size_t)(b * SEQ + t)) * DM + h * HD + dj * 16 + lo] = f2bf(O[dj][r] * li);
    }
}

extern "C" void kernel_launch(void* const* d_in, const int* in_sizes, int n_in,
                              void* d_out, int out_size, void* d_ws, size_t ws_size,
                              hipStream_t stream) {
    const float* x   = (const float*)d_in[0];
    const int*   pos = (const int*)d_in[1];
    const float* qw  = (const float*)d_in[2];
    const float* qb  = (const float*)d_in[3];
    const float* kw  = (const float*)d_in[4];
    const float* kb  = (const float*)d_in[5];
    const float* vw  = (const float*)d_in[6];
    const float* vb  = (const float*)d_in[7];
    const float* ow  = (const float*)d_in[8];
    const float* ob  = (const float*)d_in[9];
    float* out = (float*)d_out;                 // OUTPUT IS FP32

    u16* xb    = (u16*)d_ws;                                    // 6291456
    u16* Wqkvt = xb    + (size_t)8192 * DM;                     //  983040
    u16* Wot   = Wqkvt + (size_t)1280 * DM;                     //  589824
    u16* Qbuf  = Wot   + (size_t)DM * DM;                       // 6291456 (rope'd)
    u16* Kbuf  = Qbuf  + (size_t)BATCH * NHEAD * SEQ * HD;      // 2097152 (rope'd)
    u16* Vtb   = Kbuf  + (size_t)BATCH * KVH * SEQ * HD;        // 2097152 [b,g,d,s]
    u16* attn  = xb;     // alias: xb dead after gemm_qkv

    const int NCVT = 8192 * DM / 4 + 1280 * DM + DM * DM;
    cvt_all<<<(NCVT + 255) / 256, 256, 0, stream>>>(x, qw, kw, vw, ow, xb, Wqkvt, Wot);

    gemm_qkv<<<1280, 256, 0, stream>>>(xb, Wqkvt, qb, kb, vb, pos, Qbuf, Kbuf, Vtb);

    attn_mfma<<<1536, 256, 0, stream>>>(Qbuf, Kbuf, Vtb, attn);

    gemm_oproj<<<768, 256, 0, stream>>>(attn, Wot, ob, out);
}

// Round 14
// 194.848 us; speedup vs baseline: 1.1077x; 1.0075x over previous
//
#include <hip/hip_runtime.h>
#include <hip/hip_bf16.h>
#include <math.h>

#define BATCH 8
#define SEQ   1024
#define DM    768
#define NHEAD 12
#define KVH   4
#define HD    64
#define REP   3

// softmax scale folded into Q weights, exp2 domain: 0.125 * log2(e)
#define QSCALE 0.18033688011112042f
// RoPE: inv_freq(j) = exp2(-j * LOG2_BASE_OVER_HALF / 32), j in [0,32)
#define ROPE_C (13.287712379549449f / 32.0f)

typedef unsigned short u16;
typedef __attribute__((ext_vector_type(8))) __bf16 bf16x8;
typedef __attribute__((ext_vector_type(4))) float f32x4;
typedef __attribute__((ext_vector_type(4))) unsigned int u32x4;
typedef __attribute__((address_space(1))) const unsigned int gu32_c;
typedef __attribute__((address_space(3))) unsigned int su32;

// RTNE fp32 -> bf16 (finite values)
__device__ __forceinline__ u16 f2bf(float f) {
    unsigned int u = __float_as_uint(f);
    u += 0x7fffu + ((u >> 16) & 1u);
    return (u16)(u >> 16);
}

// ======== fused converts: x->bf16, Wqkv^T (Q cols pre-scaled), Wo^T ==========
__global__ __launch_bounds__(256) void cvt_all(
    const float* __restrict__ x,
    const float* __restrict__ qw, const float* __restrict__ kw,
    const float* __restrict__ vw, const float* __restrict__ ow,
    u16* __restrict__ xb, u16* __restrict__ wqkvt, u16* __restrict__ wot)
{
    const int NX = 8192 * DM / 4;          // float4 items
    const int NW = 1280 * DM;
    const int NO = DM * DM;
    const int i = blockIdx.x * 256 + threadIdx.x;
    if (i < NX) {
        const float4 v = ((const float4*)x)[i];
        ushort4 r;
        r.x = f2bf(v.x); r.y = f2bf(v.y); r.z = f2bf(v.z); r.w = f2bf(v.w);
        ((ushort4*)xb)[i] = r;
    } else if (i < NX + NW) {
        const int idx = i - NX;                // idx = n*768 + k
        const int k = idx % DM;
        const int n = idx / DM;
        float v;
        if (n < 768)       v = qw[(size_t)k * 768 + n] * QSCALE;
        else if (n < 1024) v = kw[(size_t)k * 256 + (n - 768)];
        else               v = vw[(size_t)k * 256 + (n - 1024)];
        wqkvt[idx] = f2bf(v);
    } else if (i < NX + NW + NO) {
        const int idx = i - NX - NW;
        const int k = idx % DM;
        const int n = idx / DM;
        wot[idx] = f2bf(ow[(size_t)k * DM + n]);
    }
}

// ======== 64x128-tile bf16 MFMA GEMM body: ring-4 counted-vmcnt pipeline ====
__device__ __forceinline__ void gemm64_body(
    const u16* __restrict__ A, const u16* __restrict__ B,
    int m0, int n0, u16 (*As)[2048], u16 (*Bs)[4096], f32x4 acc[2][4])
{
    const int tid  = threadIdx.x;
    const int lane = tid & 63;
    const int wid  = tid >> 6;
    const int wr = wid >> 1, wc = wid & 1;
    const int lo = lane & 15, hi = lane >> 4;

    const f32x4 z = {0.f, 0.f, 0.f, 0.f};
    #pragma unroll
    for (int i = 0; i < 2; i++)
        #pragma unroll
        for (int j = 0; j < 4; j++)
            acc[i][j] = z;

    const int NT = DM / 32;                   // 24 K-steps
    const int rowA = tid >> 2;
    const int colA = (tid & 3) << 3;

    #define STAGE_G(kt_, sl_) do {                                            \
        __builtin_amdgcn_global_load_lds(                                     \
            (gu32_c*)&A[(size_t)(m0 + rowA) * DM + (kt_) * 32 + colA],        \
            (su32*)&As[sl_][wid << 9], 16, 0, 0);                             \
        _Pragma("unroll")                                                     \
        for (int r_ = 0; r_ < 2; ++r_) {                                      \
            const int idx_  = r_ * 256 + tid;                                 \
            const int row_  = idx_ >> 2;                                      \
            const int col_  = (idx_ & 3) << 3;                                \
            const int base_ = (r_ * 256 + wid * 64) * 8;                      \
            __builtin_amdgcn_global_load_lds(                                 \
                (gu32_c*)&B[(size_t)(n0 + row_) * DM + (kt_) * 32 + col_],    \
                (su32*)&Bs[sl_][base_], 16, 0, 0);                            \
        }                                                                     \
    } while (0)

    STAGE_G(0, 0);
    STAGE_G(1, 1);

    for (int kt = 0; kt < NT; ++kt) {
        const int k2 = (kt + 2 < NT) ? kt + 2 : NT - 1;   // clamp: never read
        STAGE_G(k2, (kt + 2) & 3);
        asm volatile("s_waitcnt vmcnt(6)" ::: "memory");
        __builtin_amdgcn_s_barrier();
        __builtin_amdgcn_sched_barrier(0);

        const int sl = kt & 3;
        bf16x8 af[2], bfr[4];
        #pragma unroll
        for (int i = 0; i < 2; i++) af[i]  = *(const bf16x8*)&As[sl][(wr * 32 + i * 16 + lo) * 32 + hi * 8];
        #pragma unroll
        for (int j = 0; j < 4; j++) bfr[j] = *(const bf16x8*)&Bs[sl][(wc * 64 + j * 16 + lo) * 32 + hi * 8];
        #pragma unroll
        for (int i = 0; i < 2; i++)
            #pragma unroll
            for (int j = 0; j < 4; j++)
                acc[i][j] = __builtin_amdgcn_mfma_f32_16x16x32_bf16(af[i], bfr[j], acc[i][j], 0, 0, 0);
    }
    #undef STAGE_G
}

// ======== QKV projection with FUSED RoPE ====================================
// Fast trig: __sinf/__cosf (v_sin/v_cos).  arg <= 1023 rad -> fract-of-rev
// loses ~8 mantissa bits -> |err| ~5e-5, invisible at bf16 (ulp 7.8e-3).
__global__ __launch_bounds__(256, 2) void gemm_qkv(
    const u16* __restrict__ xb, const u16* __restrict__ wt,
    const float* __restrict__ qb, const float* __restrict__ kb,
    const float* __restrict__ vb, const int* __restrict__ pos,
    u16* __restrict__ Q, u16* __restrict__ K, u16* __restrict__ Vt)
{
    __shared__ __align__(16) u16 As[4][2048];
    __shared__ __align__(16) u16 Bs[4][4096];
    const int id = (blockIdx.x & 7) * 160 + (blockIdx.x >> 3);
    const int m0 = (id / 10) * 64;
    const int n0 = (id % 10) * 128;
    f32x4 acc[2][4];
    gemm64_body(xb, wt, m0, n0, As, Bs, acc);

    const int tid = threadIdx.x;
    const int lane = tid & 63, wid = tid >> 6;
    const int wr = wid >> 1, wc = wid & 1;
    const int lo = lane & 15, hi = lane >> 4;

    const int seg = n0 + wc * 64;            // wave-uniform, 64-aligned

    if (seg >= 1024) {
        // V: [b,g,d,t], ushort4 stores (4 consecutive t)
        #pragma unroll
        for (int j = 0; j < 4; j++) {
            const int nl = seg - 1024 + j * 16 + lo;
            const float bias = vb[nl];
            const int head = nl >> 6, d = nl & 63;
            #pragma unroll
            for (int i = 0; i < 2; i++) {
                ushort4 vs;
                vs.x = f2bf(acc[i][j][0] + bias);
                vs.y = f2bf(acc[i][j][1] + bias);
                vs.z = f2bf(acc[i][j][2] + bias);
                vs.w = f2bf(acc[i][j][3] + bias);
                const int m = m0 + wr * 32 + i * 16 + hi * 4;
                const int b = m >> 10, t = m & 1023;
                *(ushort4*)&Vt[(((size_t)(b * KVH + head)) * HD + d) * SEQ + t] = vs;
            }
        }
    } else {
        const bool isQ = seg < 768;
        const int  segl = isQ ? seg : seg - 768;
        const int  head = segl >> 6;
        const int  Hcnt = isQ ? NHEAD : KVH;
        u16* outp = isQ ? Q : K;
        float bias[4];
        #pragma unroll
        for (int j = 0; j < 4; j++) {
            const int nl = segl + j * 16 + lo;
            bias[j] = isQ ? qb[nl] * QSCALE : kb[nl];
        }
        const float inv0 = exp2f(-(float)lo * ROPE_C);
        const float inv1 = exp2f(-(float)(16 + lo) * ROPE_C);
        int pmode;                             // pos dtype robustness
        if (pos[1] == 1)                         pmode = 0;
        else if (((const float*)pos)[1] == 1.0f) pmode = 1;
        else                                     pmode = 2;
        const int src0 = (hi << 4) | (lo >> 1);
        const int src1 = src0 | 8;
        const bool odd = (lo & 1) != 0;

        #pragma unroll
        for (int i = 0; i < 2; i++) {
            #pragma unroll
            for (int r = 0; r < 4; r++) {
                const float v0 = acc[i][0][r] + bias[0];
                const float v1 = acc[i][1][r] + bias[1];
                const float v2 = acc[i][2][r] + bias[2];
                const float v3 = acc[i][3][r] + bias[3];
                const float p0e = __shfl(v1, src0), p0o = __shfl(v3, src0);
                const float p1e = __shfl(v1, src1), p1o = __shfl(v3, src1);
                const float p2e = __shfl(v0, src0), p2o = __shfl(v2, src0);
                const float p3e = __shfl(v0, src1), p3o = __shfl(v2, src1);
                const float px0 = odd ? p0o : p0e;
                const float px1 = odd ? p1o : p1e;
                const float px2 = odd ? p2o : p2e;
                const float px3 = odd ? p3o : p3e;

                const int m = m0 + wr * 32 + i * 16 + hi * 4 + r;
                const int b = m >> 10, t = m & 1023;
                float pp;
                if (pmode == 0)      pp = (float)pos[t];
                else if (pmode == 1) pp = ((const float*)pos)[t];
                else                 pp = (float)pos[2 * t];

                const float a0 = pp * inv0, a1 = pp * inv1;
                const float sv0 = __sinf(a0), cv0 = __cosf(a0);
                const float sv1 = __sinf(a1), cv1 = __cosf(a1);
                const float o0 = v0 * cv0 - px0 * sv0;
                const float o1 = v1 * cv1 - px1 * sv1;
                const float o2 = v2 * cv0 + px2 * sv0;
                const float o3 = v3 * cv1 + px3 * sv1;

                u16* dst = outp + ((size_t)(b * Hcnt + head) * SEQ + t) * HD;
                dst[lo]      = f2bf(o0);
                dst[16 + lo] = f2bf(o1);
                dst[32 + lo] = f2bf(o2);
                dst[48 + lo] = f2bf(o3);
            }
        }
    }
}

// ======== output projection: grid 768 = 8 XCD x 96 (exactly 3 blocks/CU) ====
__global__ __launch_bounds__(256, 2) void gemm_oproj(
    const u16* __restrict__ Ab, const u16* __restrict__ wt,
    const float* __restrict__ ob, float* __restrict__ outp)
{
    __shared__ __align__(16) u16 As[4][2048];
    __shared__ __align__(16) u16 Bs[4][4096];
    const int id = (blockIdx.x & 7) * 96 + (blockIdx.x >> 3);
    const int m0 = (id / 6) * 64;
    const int n0 = (id % 6) * 128;
    f32x4 acc[2][4];
    gemm64_body(Ab, wt, m0, n0, As, Bs, acc);

    const int tid = threadIdx.x;
    const int lane = tid & 63, wid = tid >> 6;
    const int wr = wid >> 1, wc = wid & 1;
    const int lo = lane & 15, hi = lane >> 4;

    #pragma unroll
    for (int j = 0; j < 4; j++) {
        const int n = n0 + wc * 64 + j * 16 + lo;
        const float bias = ob[n];
        #pragma unroll
        for (int i = 0; i < 2; i++) {
            #pragma unroll
            for (int r = 0; r < 4; r++) {
                const int m = m0 + wr * 32 + i * 16 + hi * 4 + r;
                outp[(size_t)m * DM + n] = acc[i][j][r] + bias;
            }
        }
    }
}

// ======== flash attention v10: 32 q-rows/wave (adjacent strip pair) =========
// Block = (b, h, superblock a) of 128 q-rows; wave wid owns strips
// w0 = 8a+2wid and w0+1 (32 rows).  w0 even -> BOTH strips share the SAME
// diagonal tile dT = 4a+wid and trip range -> zero divergence between frags;
// all waves of a block share the tile range (spans differ <=3 of 4a+4).
// vs v9: per-head staging bytes HALVED (8 blocks re-stage not 16), barriers/
// loop/addr overhead halved per q-row, 16 MFMA per barrier (was 8).
// Grid 768, LPT (a descending per XCD), LDS 32KB x 3 blocks/CU.
__device__ __forceinline__ void strip_compute(
    const bf16x8& qf0, const bf16x8& qf1,
    const bf16x8& k0, const bf16x8& k1, const bf16x8& k2, const bf16x8& k3,
    const bf16x8* vv, bool diag, int msk0, int hi,
    float& m, float& l, f32x4* O)
{
    const f32x4 z = {0.f, 0.f, 0.f, 0.f};
    f32x4 a0 = z, a1 = z;
    __builtin_amdgcn_s_setprio(1);
    a0 = __builtin_amdgcn_mfma_f32_16x16x32_bf16(k0, qf0, a0, 0, 0, 0);
    a0 = __builtin_amdgcn_mfma_f32_16x16x32_bf16(k1, qf1, a0, 0, 0, 0);
    a1 = __builtin_amdgcn_mfma_f32_16x16x32_bf16(k2, qf0, a1, 0, 0, 0);
    a1 = __builtin_amdgcn_mfma_f32_16x16x32_bf16(k3, qf1, a1, 0, 0, 0);
    __builtin_amdgcn_s_setprio(0);

    float sc[8];
    #pragma unroll
    for (int e = 0; e < 8; ++e)
        sc[e] = (e < 4) ? a0[e & 3] : a1[e & 3];
    if (diag) {
        #pragma unroll
        for (int e = 0; e < 8; ++e) {
            const int srel = ((e >> 2) << 4) + (hi << 2) + (e & 3);
            if (srel > msk0) sc[e] = -3.0e38f;
        }
    }
    float pm = sc[0];
    #pragma unroll
    for (int e = 1; e < 8; ++e) pm = fmaxf(pm, sc[e]);

    if (!__all(pm - m <= 8.0f)) {            // defer-max (per-lane == per-row)
        float pr = fmaxf(pm, __shfl_xor(pm, 16));
        pr = fmaxf(pr, __shfl_xor(pr, 32));
        const float mn = fmaxf(m, pr);
        const float f = exp2f(m - mn);       // first tile: m=-3e38 -> f=0
        l *= f;
        #pragma unroll
        for (int r = 0; r < 4; ++r) {
            const float fr = __shfl(f, hi * 4 + r);
            #pragma unroll
            for (int dj = 0; dj < 4; ++dj) O[dj][r] *= fr;
        }
        m = mn;
    }

    union { u16 u[8]; bf16x8 v; } pu;
    float ps = 0.f;
    #pragma unroll
    for (int e = 0; e < 8; ++e) {
        const float p = exp2f(sc[e] - m);    // bounded by 2^8
        ps += p;
        pu.u[e] = f2bf(p);
    }
    l += ps;                                  // per-lane partial

    __builtin_amdgcn_s_setprio(1);
    #pragma unroll
    for (int dj = 0; dj < 4; ++dj)
        O[dj] = __builtin_amdgcn_mfma_f32_16x16x32_bf16(pu.v, vv[dj], O[dj], 0, 0, 0);
    __builtin_amdgcn_s_setprio(0);
}

__global__ __launch_bounds__(256, 3) void attn_mfma(
    const u16* __restrict__ Q, const u16* __restrict__ K,
    const u16* __restrict__ Vt, u16* __restrict__ outp)
{
    __shared__ __align__(16) u16 Ks[4][2048];   // ring-4: 32 s x 64 d, swizzled
    __shared__ __align__(16) u16 Vs[4][2048];   // ring-4: 64 d x 32 s, permuted

    const int blk = blockIdx.x;                  // 768 = 8b*12h*8a
    const int xcd = blk & 7;
    const int jj  = blk >> 3;                    // 0..95
    const int bg  = (xcd << 2) + (jj & 3);       // 0..31
    const int rh  = jj >> 2;                     // 0..23
    const int a   = 7 - rh / 3;                  // q-superblock, DESCENDING (LPT)
    const int hl  = rh % 3;
    const int b   = bg >> 2, g = bg & 3;
    const int h   = g * REP + hl;

    const int wid  = threadIdx.x >> 6;
    const int lane = threadIdx.x & 63;
    const int lo = lane & 15, hi = lane >> 4;

    const int w0   = (a << 3) + (wid << 1);      // even strip; pair = w0, w0+1
    const int q0   = w0 << 4;                    // 32 q-rows [q0, q0+32)
    const int dT   = (a << 2) + wid;             // shared diagonal tile
    const int mskA = lo;                         // w0 even
    const int mskB = 16 + lo;                    // w0+1 odd
    const int nstT = (a << 2) + 4;               // block trip count (= max dT+1)

    const u16* Kp = K  + (size_t)(b * KVH + g) * SEQ * HD;
    const u16* Vp = Vt + (size_t)(b * KVH + g) * SEQ * HD;   // [d][s]

    const int jK = (wid << 6) + lane;
    const int sKoff = (jK ^ ((jK >> 3) & 7)) << 3;           // u16 offset
    int vsoff[4];
    #pragma unroll
    for (int q = 0; q < 4; ++q) {
        const int dw  = (wid << 8) + (q << 6) + lane;
        const int R   = dw >> 4;
        const int wd  = dw & 15;
        const int hpl = (wd >> 2) ^ ((R >> 1) & 3);
        vsoff[q] = (R << 10) + (hpl << 2) + (((wd >> 1) & 1) << 4) + ((wd & 1) << 1);
    }

    const u16* QpA = Q + ((size_t)(b * NHEAD + h) * SEQ + q0) * HD;
    const u16* QpB = QpA + (size_t)16 * HD;
    const bf16x8 qA0 = *(const bf16x8*)&QpA[(size_t)lo * HD + hi * 8];
    const bf16x8 qA1 = *(const bf16x8*)&QpA[(size_t)lo * HD + 32 + hi * 8];
    const bf16x8 qB0 = *(const bf16x8*)&QpB[(size_t)lo * HD + hi * 8];
    const bf16x8 qB1 = *(const bf16x8*)&QpB[(size_t)lo * HD + 32 + hi * 8];

    const f32x4 z = {0.f, 0.f, 0.f, 0.f};
    f32x4 OA[4], OB[4];
    #pragma unroll
    for (int dj = 0; dj < 4; ++dj) { OA[dj] = z; OB[dj] = z; }
    float mA = -3.0e38f, lA = 0.f, mB = -3.0e38f, lB = 0.f;

    #define STAGE(st_, sl_) do {                                              \
        const int s0_ = (st_) << 5;                                           \
        __builtin_amdgcn_global_load_lds(                                     \
            (gu32_c*)(Kp + (s0_ << 6) + sKoff),                               \
            (su32*)&Ks[sl_][wid << 9], 16, 0, 0);                             \
        _Pragma("unroll")                                                     \
        for (int q_ = 0; q_ < 4; ++q_)                                        \
            __builtin_amdgcn_global_load_lds(                                 \
                (gu32_c*)(Vp + s0_ + vsoff[q_]),                              \
                (su32*)&Vs[sl_][(wid << 9) + (q_ << 7)], 4, 0, 0);            \
    } while (0)

    STAGE(0, 0);
    STAGE(1, 1);

    const int xorK = lo & 7;
    for (int st = 0; st < nstT; ++st) {
        const int s2 = (st + 2 < nstT) ? st + 2 : nstT - 1;  // clamp: never read
        STAGE(s2, (st + 2) & 3);
        asm volatile("s_waitcnt vmcnt(10)" ::: "memory");
        __builtin_amdgcn_s_barrier();
        __builtin_amdgcn_sched_barrier(0);

        if (st <= dT) {
            const int sl = st & 3;
            const u16* kb_ = Ks[sl];
            const bf16x8 k0 = *(const bf16x8*)&kb_[((lo << 3) + (hi ^ xorK)) << 3];
            const bf16x8 k1 = *(const bf16x8*)&kb_[((lo << 3) + ((4 + hi) ^ xorK)) << 3];
            const bf16x8 k2 = *(const bf16x8*)&kb_[(((16 + lo) << 3) + (hi ^ xorK)) << 3];
            const bf16x8 k3 = *(const bf16x8*)&kb_[(((16 + lo) << 3) + ((4 + hi) ^ xorK)) << 3];
            bf16x8 vv[4];
            #pragma unroll
            for (int dj = 0; dj < 4; ++dj) {
                const int R = dj * 16 + lo;
                vv[dj] = *(const bf16x8*)&Vs[sl][(R << 5) + ((hi ^ ((R >> 1) & 3)) << 3)];
            }
            const bool diag = (st == dT);
            strip_compute(qA0, qA1, k0, k1, k2, k3, vv, diag, mskA, hi, mA, lA, OA);
            strip_compute(qB0, qB1, k0, k1, k2, k3, vv, diag, mskB, hi, mB, lB, OB);
        }
    }
    #undef STAGE

    // epilogue: reduce per-lane l across hi-groups, then per-row store
    lA += __shfl_xor(lA, 16); lA += __shfl_xor(lA, 32);
    lB += __shfl_xor(lB, 16); lB += __shfl_xor(lB, 32);
    #pragma unroll
    for (int r = 0; r < 4; ++r) {
        const float liA = 1.0f / fmaxf(__shfl(lA, hi * 4 + r), 1e-37f);
        const float liB = 1.0f / fmaxf(__shfl(lB, hi * 4 + r), 1e-37f);
        const int tA = q0 + hi * 4 + r;
        const int tB = tA + 16;
        #pragma unroll
        for (int dj = 0; dj < 4; ++dj) {
            outp[((size_t)(b * SEQ + tA)) * DM + h * HD + dj * 16 + lo] = f2bf(OA[dj][r] * liA);
            outp[((size_t)(b * SEQ + tB)) * DM + h * HD + dj * 16 + lo] = f2bf(OB[dj][r] * liB);
        }
    }
}

extern "C" void kernel_launch(void* const* d_in, const int* in_sizes, int n_in,
                              void* d_out, int out_size, void* d_ws, size_t ws_size,
                              hipStream_t stream) {
    const float* x   = (const float*)d_in[0];
    const int*   pos = (const int*)d_in[1];
    const float* qw  = (const float*)d_in[2];
    const float* qb  = (const float*)d_in[3];
    const float* kw  = (const float*)d_in[4];
    const float* kb  = (const float*)d_in[5];
    const float* vw  = (const float*)d_in[6];
    const float* vb  = (const float*)d_in[7];
    const float* ow  = (const float*)d_in[8];
    const float* ob  = (const float*)d_in[9];
    float* out = (float*)d_out;                 // OUTPUT IS FP32

    u16* xb    = (u16*)d_ws;                                    // 6291456
    u16* Wqkvt = xb    + (size_t)8192 * DM;                     //  983040
    u16* Wot   = Wqkvt + (size_t)1280 * DM;                     //  589824
    u16* Qbuf  = Wot   + (size_t)DM * DM;                       // 6291456 (rope'd)
    u16* Kbuf  = Qbuf  + (size_t)BATCH * NHEAD * SEQ * HD;      // 2097152 (rope'd)
    u16* Vtb   = Kbuf  + (size_t)BATCH * KVH * SEQ * HD;        // 2097152 [b,g,d,s]
    u16* attn  = xb;     // alias: xb dead after gemm_qkv

    const int NCVT = 8192 * DM / 4 + 1280 * DM + DM * DM;
    cvt_all<<<(NCVT + 255) / 256, 256, 0, stream>>>(x, qw, kw, vw, ow, xb, Wqkvt, Wot);

    gemm_qkv<<<1280, 256, 0, stream>>>(xb, Wqkvt, qb, kb, vb, pos, Qbuf, Kbuf, Vtb);

    attn_mfma<<<768, 256, 0, stream>>>(Qbuf, Kbuf, Vtb, attn);

    gemm_oproj<<<768, 256, 0, stream>>>(attn, Wot, ob, out);
}

// Round 15
// 192.453 us; speedup vs baseline: 1.1215x; 1.0124x over previous
//
#include <hip/hip_runtime.h>
#include <hip/hip_bf16.h>
#include <math.h>

#define BATCH 8
#define SEQ   1024
#define DM    768
#define NHEAD 12
#define KVH   4
#define HD    64
#define REP   3

// softmax scale folded into Q weights, exp2 domain: 0.125 * log2(e)
#define QSCALE 0.18033688011112042f
// RoPE: inv_freq(j) = exp2(-j * LOG2_BASE_OVER_HALF / 32), j in [0,32)
#define ROPE_C (13.287712379549449f / 32.0f)

typedef unsigned short u16;
typedef __attribute__((ext_vector_type(8))) __bf16 bf16x8;
typedef __attribute__((ext_vector_type(4))) float f32x4;
typedef __attribute__((ext_vector_type(4))) unsigned int u32x4;
typedef __attribute__((address_space(1))) const unsigned int gu32_c;
typedef __attribute__((address_space(3))) unsigned int su32;

// RTNE fp32 -> bf16 (finite values)
__device__ __forceinline__ u16 f2bf(float f) {
    unsigned int u = __float_as_uint(f);
    u += 0x7fffu + ((u >> 16) & 1u);
    return (u16)(u >> 16);
}

// ======== fused converts: x->bf16, Wqkv^T (Q cols pre-scaled), Wo^T ==========
__global__ __launch_bounds__(256) void cvt_all(
    const float* __restrict__ x,
    const float* __restrict__ qw, const float* __restrict__ kw,
    const float* __restrict__ vw, const float* __restrict__ ow,
    u16* __restrict__ xb, u16* __restrict__ wqkvt, u16* __restrict__ wot)
{
    const int NX = 8192 * DM / 4;          // float4 items
    const int NW = 1280 * DM;
    const int NO = DM * DM;
    const int i = blockIdx.x * 256 + threadIdx.x;
    if (i < NX) {
        const float4 v = ((const float4*)x)[i];
        ushort4 r;
        r.x = f2bf(v.x); r.y = f2bf(v.y); r.z = f2bf(v.z); r.w = f2bf(v.w);
        ((ushort4*)xb)[i] = r;
    } else if (i < NX + NW) {
        const int idx = i - NX;                // idx = n*768 + k
        const int k = idx % DM;
        const int n = idx / DM;
        float v;
        if (n < 768)       v = qw[(size_t)k * 768 + n] * QSCALE;
        else if (n < 1024) v = kw[(size_t)k * 256 + (n - 768)];
        else               v = vw[(size_t)k * 256 + (n - 1024)];
        wqkvt[idx] = f2bf(v);
    } else if (i < NX + NW + NO) {
        const int idx = i - NX - NW;
        const int k = idx % DM;
        const int n = idx / DM;
        wot[idx] = f2bf(ow[(size_t)k * DM + n]);
    }
}

// ======== 64x128-tile bf16 MFMA GEMM body: ring-4 counted-vmcnt pipeline ====
__device__ __forceinline__ void gemm64_body(
    const u16* __restrict__ A, const u16* __restrict__ B,
    int m0, int n0, u16 (*As)[2048], u16 (*Bs)[4096], f32x4 acc[2][4])
{
    const int tid  = threadIdx.x;
    const int lane = tid & 63;
    const int wid  = tid >> 6;
    const int wr = wid >> 1, wc = wid & 1;
    const int lo = lane & 15, hi = lane >> 4;

    const f32x4 z = {0.f, 0.f, 0.f, 0.f};
    #pragma unroll
    for (int i = 0; i < 2; i++)
        #pragma unroll
        for (int j = 0; j < 4; j++)
            acc[i][j] = z;

    const int NT = DM / 32;                   // 24 K-steps
    const int rowA = tid >> 2;
    const int colA = (tid & 3) << 3;

    #define STAGE_G(kt_, sl_) do {                                            \
        __builtin_amdgcn_global_load_lds(                                     \
            (gu32_c*)&A[(size_t)(m0 + rowA) * DM + (kt_) * 32 + colA],        \
            (su32*)&As[sl_][wid << 9], 16, 0, 0);                             \
        _Pragma("unroll")                                                     \
        for (int r_ = 0; r_ < 2; ++r_) {                                      \
            const int idx_  = r_ * 256 + tid;                                 \
            const int row_  = idx_ >> 2;                                      \
            const int col_  = (idx_ & 3) << 3;                                \
            const int base_ = (r_ * 256 + wid * 64) * 8;                      \
            __builtin_amdgcn_global_load_lds(                                 \
                (gu32_c*)&B[(size_t)(n0 + row_) * DM + (kt_) * 32 + col_],    \
                (su32*)&Bs[sl_][base_], 16, 0, 0);                            \
        }                                                                     \
    } while (0)

    STAGE_G(0, 0);
    STAGE_G(1, 1);

    for (int kt = 0; kt < NT; ++kt) {
        const int k2 = (kt + 2 < NT) ? kt + 2 : NT - 1;   // clamp: never read
        STAGE_G(k2, (kt + 2) & 3);
        asm volatile("s_waitcnt vmcnt(6)" ::: "memory");
        __builtin_amdgcn_s_barrier();
        __builtin_amdgcn_sched_barrier(0);

        const int sl = kt & 3;
        bf16x8 af[2], bfr[4];
        #pragma unroll
        for (int i = 0; i < 2; i++) af[i]  = *(const bf16x8*)&As[sl][(wr * 32 + i * 16 + lo) * 32 + hi * 8];
        #pragma unroll
        for (int j = 0; j < 4; j++) bfr[j] = *(const bf16x8*)&Bs[sl][(wc * 64 + j * 16 + lo) * 32 + hi * 8];
        #pragma unroll
        for (int i = 0; i < 2; i++)
            #pragma unroll
            for (int j = 0; j < 4; j++)
                acc[i][j] = __builtin_amdgcn_mfma_f32_16x16x32_bf16(af[i], bfr[j], acc[i][j], 0, 0, 0);
    }
    #undef STAGE_G
}

// ======== QKV projection with FUSED RoPE ====================================
// Fast trig: __sinf/__cosf (v_sin/v_cos).  arg <= 1023 rad -> fract-of-rev
// loses ~8 mantissa bits -> |err| ~5e-5, invisible at bf16 (ulp 7.8e-3).
__global__ __launch_bounds__(256, 2) void gemm_qkv(
    const u16* __restrict__ xb, const u16* __restrict__ wt,
    const float* __restrict__ qb, const float* __restrict__ kb,
    const float* __restrict__ vb, const int* __restrict__ pos,
    u16* __restrict__ Q, u16* __restrict__ K, u16* __restrict__ Vt)
{
    __shared__ __align__(16) u16 As[4][2048];
    __shared__ __align__(16) u16 Bs[4][4096];
    const int id = (blockIdx.x & 7) * 160 + (blockIdx.x >> 3);
    const int m0 = (id / 10) * 64;
    const int n0 = (id % 10) * 128;
    f32x4 acc[2][4];
    gemm64_body(xb, wt, m0, n0, As, Bs, acc);

    const int tid = threadIdx.x;
    const int lane = tid & 63, wid = tid >> 6;
    const int wr = wid >> 1, wc = wid & 1;
    const int lo = lane & 15, hi = lane >> 4;

    const int seg = n0 + wc * 64;            // wave-uniform, 64-aligned

    if (seg >= 1024) {
        // V: [b,g,d,t], ushort4 stores (4 consecutive t)
        #pragma unroll
        for (int j = 0; j < 4; j++) {
            const int nl = seg - 1024 + j * 16 + lo;
            const float bias = vb[nl];
            const int head = nl >> 6, d = nl & 63;
            #pragma unroll
            for (int i = 0; i < 2; i++) {
                ushort4 vs;
                vs.x = f2bf(acc[i][j][0] + bias);
                vs.y = f2bf(acc[i][j][1] + bias);
                vs.z = f2bf(acc[i][j][2] + bias);
                vs.w = f2bf(acc[i][j][3] + bias);
                const int m = m0 + wr * 32 + i * 16 + hi * 4;
                const int b = m >> 10, t = m & 1023;
                *(ushort4*)&Vt[(((size_t)(b * KVH + head)) * HD + d) * SEQ + t] = vs;
            }
        }
    } else {
        const bool isQ = seg < 768;
        const int  segl = isQ ? seg : seg - 768;
        const int  head = segl >> 6;
        const int  Hcnt = isQ ? NHEAD : KVH;
        u16* outp = isQ ? Q : K;
        float bias[4];
        #pragma unroll
        for (int j = 0; j < 4; j++) {
            const int nl = segl + j * 16 + lo;
            bias[j] = isQ ? qb[nl] * QSCALE : kb[nl];
        }
        const float inv0 = exp2f(-(float)lo * ROPE_C);
        const float inv1 = exp2f(-(float)(16 + lo) * ROPE_C);
        int pmode;                             // pos dtype robustness
        if (pos[1] == 1)                         pmode = 0;
        else if (((const float*)pos)[1] == 1.0f) pmode = 1;
        else                                     pmode = 2;
        const int src0 = (hi << 4) | (lo >> 1);
        const int src1 = src0 | 8;
        const bool odd = (lo & 1) != 0;

        #pragma unroll
        for (int i = 0; i < 2; i++) {
            #pragma unroll
            for (int r = 0; r < 4; r++) {
                const float v0 = acc[i][0][r] + bias[0];
                const float v1 = acc[i][1][r] + bias[1];
                const float v2 = acc[i][2][r] + bias[2];
                const float v3 = acc[i][3][r] + bias[3];
                const float p0e = __shfl(v1, src0), p0o = __shfl(v3, src0);
                const float p1e = __shfl(v1, src1), p1o = __shfl(v3, src1);
                const float p2e = __shfl(v0, src0), p2o = __shfl(v2, src0);
                const float p3e = __shfl(v0, src1), p3o = __shfl(v2, src1);
                const float px0 = odd ? p0o : p0e;
                const float px1 = odd ? p1o : p1e;
                const float px2 = odd ? p2o : p2e;
                const float px3 = odd ? p3o : p3e;

                const int m = m0 + wr * 32 + i * 16 + hi * 4 + r;
                const int b = m >> 10, t = m & 1023;
                float pp;
                if (pmode == 0)      pp = (float)pos[t];
                else if (pmode == 1) pp = ((const float*)pos)[t];
                else                 pp = (float)pos[2 * t];

                const float a0 = pp * inv0, a1 = pp * inv1;
                const float sv0 = __sinf(a0), cv0 = __cosf(a0);
                const float sv1 = __sinf(a1), cv1 = __cosf(a1);
                const float o0 = v0 * cv0 - px0 * sv0;
                const float o1 = v1 * cv1 - px1 * sv1;
                const float o2 = v2 * cv0 + px2 * sv0;
                const float o3 = v3 * cv1 + px3 * sv1;

                u16* dst = outp + ((size_t)(b * Hcnt + head) * SEQ + t) * HD;
                dst[lo]      = f2bf(o0);
                dst[16 + lo] = f2bf(o1);
                dst[32 + lo] = f2bf(o2);
                dst[48 + lo] = f2bf(o3);
            }
        }
    }
}

// ======== output projection: grid 768 = 8 XCD x 96 (exactly 3 blocks/CU) ====
__global__ __launch_bounds__(256, 2) void gemm_oproj(
    const u16* __restrict__ Ab, const u16* __restrict__ wt,
    const float* __restrict__ ob, float* __restrict__ outp)
{
    __shared__ __align__(16) u16 As[4][2048];
    __shared__ __align__(16) u16 Bs[4][4096];
    const int id = (blockIdx.x & 7) * 96 + (blockIdx.x >> 3);
    const int m0 = (id / 6) * 64;
    const int n0 = (id % 6) * 128;
    f32x4 acc[2][4];
    gemm64_body(Ab, wt, m0, n0, As, Bs, acc);

    const int tid = threadIdx.x;
    const int lane = tid & 63, wid = tid >> 6;
    const int wr = wid >> 1, wc = wid & 1;
    const int lo = lane & 15, hi = lane >> 4;

    #pragma unroll
    for (int j = 0; j < 4; j++) {
        const int n = n0 + wc * 64 + j * 16 + lo;
        const float bias = ob[n];
        #pragma unroll
        for (int i = 0; i < 2; i++) {
            #pragma unroll
            for (int r = 0; r < 4; r++) {
                const int m = m0 + wr * 32 + i * 16 + hi * 4 + r;
                outp[(size_t)m * DM + n] = acc[i][j][r] + bias;
            }
        }
    }
}

// ======== flash attention v9 (r10-best, RESTORED): row-split waves, LPT =====
// Block = (b, h, q-block a) of 64 q-rows; 4 waves each own 16 rows.  All
// waves share the SAME tile range (spans differ <=1): ~97% slot utilization.
// Grid 1536 -> ~5 blocks/CU resident (LDS-capped).  v10's 32-rows/wave
// (grid 768) REGRESSED 43.6->48.7: staging was already L2-absorbed and the
// fatter tile halved resident blocks while doubling per-barrier VALU.
__device__ __forceinline__ void strip_compute(
    const bf16x8& qf0, const bf16x8& qf1,
    const bf16x8& k0, const bf16x8& k1, const bf16x8& k2, const bf16x8& k3,
    const bf16x8* vv, bool diag, int msk0, int hi,
    float& m, float& l, f32x4* O)
{
    const f32x4 z = {0.f, 0.f, 0.f, 0.f};
    f32x4 a0 = z, a1 = z;
    __builtin_amdgcn_s_setprio(1);
    a0 = __builtin_amdgcn_mfma_f32_16x16x32_bf16(k0, qf0, a0, 0, 0, 0);
    a0 = __builtin_amdgcn_mfma_f32_16x16x32_bf16(k1, qf1, a0, 0, 0, 0);
    a1 = __builtin_amdgcn_mfma_f32_16x16x32_bf16(k2, qf0, a1, 0, 0, 0);
    a1 = __builtin_amdgcn_mfma_f32_16x16x32_bf16(k3, qf1, a1, 0, 0, 0);
    __builtin_amdgcn_s_setprio(0);

    float sc[8];
    #pragma unroll
    for (int e = 0; e < 8; ++e)
        sc[e] = (e < 4) ? a0[e & 3] : a1[e & 3];
    if (diag) {
        #pragma unroll
        for (int e = 0; e < 8; ++e) {
            const int srel = ((e >> 2) << 4) + (hi << 2) + (e & 3);
            if (srel > msk0) sc[e] = -3.0e38f;
        }
    }
    float pm = sc[0];
    #pragma unroll
    for (int e = 1; e < 8; ++e) pm = fmaxf(pm, sc[e]);

    if (!__all(pm - m <= 8.0f)) {            // defer-max (per-lane == per-row)
        float pr = fmaxf(pm, __shfl_xor(pm, 16));
        pr = fmaxf(pr, __shfl_xor(pr, 32));
        const float mn = fmaxf(m, pr);
        const float f = exp2f(m - mn);       // first tile: m=-3e38 -> f=0
        l *= f;
        #pragma unroll
        for (int r = 0; r < 4; ++r) {
            const float fr = __shfl(f, hi * 4 + r);
            #pragma unroll
            for (int dj = 0; dj < 4; ++dj) O[dj][r] *= fr;
        }
        m = mn;
    }

    union { u16 u[8]; bf16x8 v; } pu;
    float ps = 0.f;
    #pragma unroll
    for (int e = 0; e < 8; ++e) {
        const float p = exp2f(sc[e] - m);    // bounded by 2^8
        ps += p;
        pu.u[e] = f2bf(p);
    }
    l += ps;                                  // per-lane partial

    __builtin_amdgcn_s_setprio(1);
    #pragma unroll
    for (int dj = 0; dj < 4; ++dj)
        O[dj] = __builtin_amdgcn_mfma_f32_16x16x32_bf16(pu.v, vv[dj], O[dj], 0, 0, 0);
    __builtin_amdgcn_s_setprio(0);
}

__global__ __launch_bounds__(256, 4) void attn_mfma(
    const u16* __restrict__ Q, const u16* __restrict__ K,
    const u16* __restrict__ Vt, u16* __restrict__ outp)
{
    __shared__ __align__(16) u16 Ks[4][2048];   // ring-4: 32 s x 64 d, swizzled
    __shared__ __align__(16) u16 Vs[4][2048];   // ring-4: 64 d x 32 s, permuted

    const int blk = blockIdx.x;                  // 1536 = 8b*12h*16a
    const int xcd = blk & 7;
    const int jj  = blk >> 3;                    // 0..191
    const int bg  = (xcd << 2) + (jj & 3);       // 0..31
    const int rh  = jj >> 2;                     // 0..47
    const int a   = 15 - rh / 3;                 // q-block, DESCENDING (LPT)
    const int hl  = rh % 3;
    const int b   = bg >> 2, g = bg & 3;
    const int h   = g * REP + hl;

    const int wid  = threadIdx.x >> 6;
    const int lane = threadIdx.x & 63;
    const int lo = lane & 15, hi = lane >> 4;

    const int w    = (a << 2) + wid;             // strip 0..63 (16 q-rows)
    const int q0   = w << 4;
    const int dT   = w >> 1;                     // last tile for this strip
    const int msk0 = lo + ((w & 1) << 4);
    const int nstT = (a << 1) + 2;               // block trip count (= max dT+1)

    const u16* Kp = K  + (size_t)(b * KVH + g) * SEQ * HD;
    const u16* Vp = Vt + (size_t)(b * KVH + g) * SEQ * HD;   // [d][s]

    const int jK = (wid << 6) + lane;
    const int sKoff = (jK ^ ((jK >> 3) & 7)) << 3;           // u16 offset
    int vsoff[4];
    #pragma unroll
    for (int q = 0; q < 4; ++q) {
        const int dw  = (wid << 8) + (q << 6) + lane;
        const int R   = dw >> 4;
        const int wd  = dw & 15;
        const int hpl = (wd >> 2) ^ ((R >> 1) & 3);
        vsoff[q] = (R << 10) + (hpl << 2) + (((wd >> 1) & 1) << 4) + ((wd & 1) << 1);
    }

    const u16* Qp = Q + ((size_t)(b * NHEAD + h) * SEQ + q0) * HD;
    const bf16x8 qf0 = *(const bf16x8*)&Qp[(size_t)lo * HD + hi * 8];
    const bf16x8 qf1 = *(const bf16x8*)&Qp[(size_t)lo * HD + 32 + hi * 8];

    const f32x4 z = {0.f, 0.f, 0.f, 0.f};
    f32x4 O[4];
    #pragma unroll
    for (int dj = 0; dj < 4; ++dj) O[dj] = z;
    float m = -3.0e38f, l = 0.f;

    #define STAGE(st_, sl_) do {                                              \
        const int s0_ = (st_) << 5;                                           \
        __builtin_amdgcn_global_load_lds(                                     \
            (gu32_c*)(Kp + (s0_ << 6) + sKoff),                               \
            (su32*)&Ks[sl_][wid << 9], 16, 0, 0);                             \
        _Pragma("unroll")                                                     \
        for (int q_ = 0; q_ < 4; ++q_)                                        \
            __builtin_amdgcn_global_load_lds(                                 \
                (gu32_c*)(Vp + s0_ + vsoff[q_]),                              \
                (su32*)&Vs[sl_][(wid << 9) + (q_ << 7)], 4, 0, 0);            \
    } while (0)

    STAGE(0, 0);
    STAGE(1, 1);

    const int xorK = lo & 7;
    for (int st = 0; st < nstT; ++st) {
        const int s2 = (st + 2 < nstT) ? st + 2 : nstT - 1;  // clamp: never read
        STAGE(s2, (st + 2) & 3);
        asm volatile("s_waitcnt vmcnt(10)" ::: "memory");
        __builtin_amdgcn_s_barrier();
        __builtin_amdgcn_sched_barrier(0);

        if (st <= dT) {
            const int sl = st & 3;
            const u16* kb_ = Ks[sl];
            const bf16x8 k0 = *(const bf16x8*)&kb_[((lo << 3) + (hi ^ xorK)) << 3];
            const bf16x8 k1 = *(const bf16x8*)&kb_[((lo << 3) + ((4 + hi) ^ xorK)) << 3];
            const bf16x8 k2 = *(const bf16x8*)&kb_[(((16 + lo) << 3) + (hi ^ xorK)) << 3];
            const bf16x8 k3 = *(const bf16x8*)&kb_[(((16 + lo) << 3) + ((4 + hi) ^ xorK)) << 3];
            bf16x8 vv[4];
            #pragma unroll
            for (int dj = 0; dj < 4; ++dj) {
                const int R = dj * 16 + lo;
                vv[dj] = *(const bf16x8*)&Vs[sl][(R << 5) + ((hi ^ ((R >> 1) & 3)) << 3)];
            }
            strip_compute(qf0, qf1, k0, k1, k2, k3, vv, st == dT, msk0, hi, m, l, O);
        }
    }
    #undef STAGE

    // epilogue: reduce per-lane l across hi-groups, then per-row store
    l += __shfl_xor(l, 16); l += __shfl_xor(l, 32);
    #pragma unroll
    for (int r = 0; r < 4; ++r) {
        const float li = 1.0f / fmaxf(__shfl(l, hi * 4 + r), 1e-37f);
        const int t = q0 + hi * 4 + r;
        #pragma unroll
        for (int dj = 0; dj < 4; ++dj)
            outp[((size_t)(b * SEQ + t)) * DM + h * HD + dj * 16 + lo] = f2bf(O[dj][r] * li);
    }
}

extern "C" void kernel_launch(void* const* d_in, const int* in_sizes, int n_in,
                              void* d_out, int out_size, void* d_ws, size_t ws_size,
                              hipStream_t stream) {
    const float* x   = (const float*)d_in[0];
    const int*   pos = (const int*)d_in[1];
    const float* qw  = (const float*)d_in[2];
    const float* qb  = (const float*)d_in[3];
    const float* kw  = (const float*)d_in[4];
    const float* kb  = (const float*)d_in[5];
    const float* vw  = (const float*)d_in[6];
    const float* vb  = (const float*)d_in[7];
    const float* ow  = (const float*)d_in[8];
    const float* ob  = (const float*)d_in[9];
    float* out = (float*)d_out;                 // OUTPUT IS FP32

    u16* xb    = (u16*)d_ws;                                    // 6291456
    u16* Wqkvt = xb    + (size_t)8192 * DM;                     //  983040
    u16* Wot   = Wqkvt + (size_t)1280 * DM;                     //  589824
    u16* Qbuf  = Wot   + (size_t)DM * DM;                       // 6291456 (rope'd)
    u16* Kbuf  = Qbuf  + (size_t)BATCH * NHEAD * SEQ * HD;      // 2097152 (rope'd)
    u16* Vtb   = Kbuf  + (size_t)BATCH * KVH * SEQ * HD;        // 2097152 [b,g,d,s]
    u16* attn  = xb;     // alias: xb dead after gemm_qkv

    const int NCVT = 8192 * DM / 4 + 1280 * DM + DM * DM;
    cvt_all<<<(NCVT + 255) / 256, 256, 0, stream>>>(x, qw, kw, vw, ow, xb, Wqkvt, Wot);

    gemm_qkv<<<1280, 256, 0, stream>>>(xb, Wqkvt, qb, kb, vb, pos, Qbuf, Kbuf, Vtb);

    attn_mfma<<<1536, 256, 0, stream>>>(Qbuf, Kbuf, Vtb, attn);

    gemm_oproj<<<768, 256, 0, stream>>>(attn, Wot, ob, out);
}

// Round 16
// 189.783 us; speedup vs baseline: 1.1372x; 1.0141x over previous
//
#include <hip/hip_runtime.h>
#include <hip/hip_bf16.h>
#include <math.h>

#define BATCH 8
#define SEQ   1024
#define DM    768
#define NHEAD 12
#define KVH   4
#define HD    64
#define REP   3

// softmax scale folded into Q weights, exp2 domain: 0.125 * log2(e)
#define QSCALE 0.18033688011112042f
// RoPE: inv_freq(j) = exp2(-j * LOG2_BASE_OVER_HALF / 32), j in [0,32)
#define ROPE_C (13.287712379549449f / 32.0f)

typedef unsigned short u16;
typedef __attribute__((ext_vector_type(8))) __bf16 bf16x8;
typedef __attribute__((ext_vector_type(4))) float f32x4;
typedef __attribute__((ext_vector_type(4))) unsigned int u32x4;
typedef __attribute__((address_space(1))) const unsigned int gu32_c;
typedef __attribute__((address_space(3))) unsigned int su32;

// RTNE fp32 -> bf16 (finite values)
__device__ __forceinline__ u16 f2bf(float f) {
    unsigned int u = __float_as_uint(f);
    u += 0x7fffu + ((u >> 16) & 1u);
    return (u16)(u >> 16);
}

// ======== fused converts: x->bf16, Wqkv^T (Q cols pre-scaled), Wo^T ==========
__global__ __launch_bounds__(256) void cvt_all(
    const float* __restrict__ x,
    const float* __restrict__ qw, const float* __restrict__ kw,
    const float* __restrict__ vw, const float* __restrict__ ow,
    u16* __restrict__ xb, u16* __restrict__ wqkvt, u16* __restrict__ wot)
{
    const int NX = 8192 * DM / 4;          // float4 items
    const int NW = 1280 * DM;
    const int NO = DM * DM;
    const int i = blockIdx.x * 256 + threadIdx.x;
    if (i < NX) {
        const float4 v = ((const float4*)x)[i];
        ushort4 r;
        r.x = f2bf(v.x); r.y = f2bf(v.y); r.z = f2bf(v.z); r.w = f2bf(v.w);
        ((ushort4*)xb)[i] = r;
    } else if (i < NX + NW) {
        const int idx = i - NX;                // idx = n*768 + k
        const int k = idx % DM;
        const int n = idx / DM;
        float v;
        if (n < 768)       v = qw[(size_t)k * 768 + n] * QSCALE;
        else if (n < 1024) v = kw[(size_t)k * 256 + (n - 768)];
        else               v = vw[(size_t)k * 256 + (n - 1024)];
        wqkvt[idx] = f2bf(v);
    } else if (i < NX + NW + NO) {
        const int idx = i - NX - NW;
        const int k = idx % DM;
        const int n = idx / DM;
        wot[idx] = f2bf(ow[(size_t)k * DM + n]);
    }
}

// ======== 64x128 GEMM body v2: ring-2, depth-1 prefetch, 2 barriers =========
// LDS 24KB (vs ring-4's 48KB) -> 6 blocks/CU: qkv's 1280 blocks (5/CU) fit in
// ONE batch (ring-4 = 3/CU = 1.67 batches, tail at partial occupancy).
// WAR safety NEEDS the trailing barrier: slot (kt+1)&1 = (kt-1)&1 is read by
// peer waves during compute(kt-1); the barrier after compute guarantees all
// reads done before any wave stages into it.  vmcnt(3) leaves batch kt+1's
// 3 loads in flight; depth-1 stall (~L2 latency - compute) hides across the
// 20-24 waves/CU this residency provides.
__device__ __forceinline__ void gemm64_body2(
    const u16* __restrict__ A, const u16* __restrict__ B,
    int m0, int n0, u16 (*As)[2048], u16 (*Bs)[4096], f32x4 acc[2][4])
{
    const int tid  = threadIdx.x;
    const int lane = tid & 63;
    const int wid  = tid >> 6;
    const int wr = wid >> 1, wc = wid & 1;
    const int lo = lane & 15, hi = lane >> 4;

    const f32x4 z = {0.f, 0.f, 0.f, 0.f};
    #pragma unroll
    for (int i = 0; i < 2; i++)
        #pragma unroll
        for (int j = 0; j < 4; j++)
            acc[i][j] = z;

    const int NT = DM / 32;                   // 24 K-steps
    const int rowA = tid >> 2;
    const int colA = (tid & 3) << 3;

    #define STAGE_G(kt_, sl_) do {                                            \
        __builtin_amdgcn_global_load_lds(                                     \
            (gu32_c*)&A[(size_t)(m0 + rowA) * DM + (kt_) * 32 + colA],        \
            (su32*)&As[sl_][wid << 9], 16, 0, 0);                             \
        _Pragma("unroll")                                                     \
        for (int r_ = 0; r_ < 2; ++r_) {                                      \
            const int idx_  = r_ * 256 + tid;                                 \
            const int row_  = idx_ >> 2;                                      \
            const int col_  = (idx_ & 3) << 3;                                \
            const int base_ = (r_ * 256 + wid * 64) * 8;                      \
            __builtin_amdgcn_global_load_lds(                                 \
                (gu32_c*)&B[(size_t)(n0 + row_) * DM + (kt_) * 32 + col_],    \
                (su32*)&Bs[sl_][base_], 16, 0, 0);                            \
        }                                                                     \
    } while (0)

    STAGE_G(0, 0);

    for (int kt = 0; kt < NT; ++kt) {
        const int k1 = (kt + 1 < NT) ? kt + 1 : NT - 1;   // clamp: never read
        STAGE_G(k1, (kt + 1) & 1);
        asm volatile("s_waitcnt vmcnt(3)" ::: "memory");
        __builtin_amdgcn_s_barrier();
        __builtin_amdgcn_sched_barrier(0);

        const int sl = kt & 1;
        bf16x8 af[2], bfr[4];
        #pragma unroll
        for (int i = 0; i < 2; i++) af[i]  = *(const bf16x8*)&As[sl][(wr * 32 + i * 16 + lo) * 32 + hi * 8];
        #pragma unroll
        for (int j = 0; j < 4; j++) bfr[j] = *(const bf16x8*)&Bs[sl][(wc * 64 + j * 16 + lo) * 32 + hi * 8];
        #pragma unroll
        for (int i = 0; i < 2; i++)
            #pragma unroll
            for (int j = 0; j < 4; j++)
                acc[i][j] = __builtin_amdgcn_mfma_f32_16x16x32_bf16(af[i], bfr[j], acc[i][j], 0, 0, 0);

        __builtin_amdgcn_s_barrier();         // WAR: protect slot before re-stage
    }
    #undef STAGE_G
}

// ======== 64x128 GEMM body: ring-4 counted-vmcnt (r9-proven, for oproj) =====
__device__ __forceinline__ void gemm64_body(
    const u16* __restrict__ A, const u16* __restrict__ B,
    int m0, int n0, u16 (*As)[2048], u16 (*Bs)[4096], f32x4 acc[2][4])
{
    const int tid  = threadIdx.x;
    const int lane = tid & 63;
    const int wid  = tid >> 6;
    const int wr = wid >> 1, wc = wid & 1;
    const int lo = lane & 15, hi = lane >> 4;

    const f32x4 z = {0.f, 0.f, 0.f, 0.f};
    #pragma unroll
    for (int i = 0; i < 2; i++)
        #pragma unroll
        for (int j = 0; j < 4; j++)
            acc[i][j] = z;

    const int NT = DM / 32;                   // 24 K-steps
    const int rowA = tid >> 2;
    const int colA = (tid & 3) << 3;

    #define STAGE_G(kt_, sl_) do {                                            \
        __builtin_amdgcn_global_load_lds(                                     \
            (gu32_c*)&A[(size_t)(m0 + rowA) * DM + (kt_) * 32 + colA],        \
            (su32*)&As[sl_][wid << 9], 16, 0, 0);                             \
        _Pragma("unroll")                                                     \
        for (int r_ = 0; r_ < 2; ++r_) {                                      \
            const int idx_  = r_ * 256 + tid;                                 \
            const int row_  = idx_ >> 2;                                      \
            const int col_  = (idx_ & 3) << 3;                                \
            const int base_ = (r_ * 256 + wid * 64) * 8;                      \
            __builtin_amdgcn_global_load_lds(                                 \
                (gu32_c*)&B[(size_t)(n0 + row_) * DM + (kt_) * 32 + col_],    \
                (su32*)&Bs[sl_][base_], 16, 0, 0);                            \
        }                                                                     \
    } while (0)

    STAGE_G(0, 0);
    STAGE_G(1, 1);

    for (int kt = 0; kt < NT; ++kt) {
        const int k2 = (kt + 2 < NT) ? kt + 2 : NT - 1;   // clamp: never read
        STAGE_G(k2, (kt + 2) & 3);
        asm volatile("s_waitcnt vmcnt(6)" ::: "memory");
        __builtin_amdgcn_s_barrier();
        __builtin_amdgcn_sched_barrier(0);

        const int sl = kt & 3;
        bf16x8 af[2], bfr[4];
        #pragma unroll
        for (int i = 0; i < 2; i++) af[i]  = *(const bf16x8*)&As[sl][(wr * 32 + i * 16 + lo) * 32 + hi * 8];
        #pragma unroll
        for (int j = 0; j < 4; j++) bfr[j] = *(const bf16x8*)&Bs[sl][(wc * 64 + j * 16 + lo) * 32 + hi * 8];
        #pragma unroll
        for (int i = 0; i < 2; i++)
            #pragma unroll
            for (int j = 0; j < 4; j++)
                acc[i][j] = __builtin_amdgcn_mfma_f32_16x16x32_bf16(af[i], bfr[j], acc[i][j], 0, 0, 0);
    }
    #undef STAGE_G
}

// ======== QKV projection with FUSED RoPE (ring-2 body: 24KB LDS, 5/CU) ======
__global__ __launch_bounds__(256, 2) void gemm_qkv(
    const u16* __restrict__ xb, const u16* __restrict__ wt,
    const float* __restrict__ qb, const float* __restrict__ kb,
    const float* __restrict__ vb, const int* __restrict__ pos,
    u16* __restrict__ Q, u16* __restrict__ K, u16* __restrict__ Vt)
{
    __shared__ __align__(16) u16 As[2][2048];
    __shared__ __align__(16) u16 Bs[2][4096];
    const int id = (blockIdx.x & 7) * 160 + (blockIdx.x >> 3);
    const int m0 = (id / 10) * 64;
    const int n0 = (id % 10) * 128;
    f32x4 acc[2][4];
    gemm64_body2(xb, wt, m0, n0, As, Bs, acc);

    const int tid = threadIdx.x;
    const int lane = tid & 63, wid = tid >> 6;
    const int wr = wid >> 1, wc = wid & 1;
    const int lo = lane & 15, hi = lane >> 4;

    const int seg = n0 + wc * 64;            // wave-uniform, 64-aligned

    if (seg >= 1024) {
        // V: [b,g,d,t], ushort4 stores (4 consecutive t)
        #pragma unroll
        for (int j = 0; j < 4; j++) {
            const int nl = seg - 1024 + j * 16 + lo;
            const float bias = vb[nl];
            const int head = nl >> 6, d = nl & 63;
            #pragma unroll
            for (int i = 0; i < 2; i++) {
                ushort4 vs;
                vs.x = f2bf(acc[i][j][0] + bias);
                vs.y = f2bf(acc[i][j][1] + bias);
                vs.z = f2bf(acc[i][j][2] + bias);
                vs.w = f2bf(acc[i][j][3] + bias);
                const int m = m0 + wr * 32 + i * 16 + hi * 4;
                const int b = m >> 10, t = m & 1023;
                *(ushort4*)&Vt[(((size_t)(b * KVH + head)) * HD + d) * SEQ + t] = vs;
            }
        }
    } else {
        const bool isQ = seg < 768;
        const int  segl = isQ ? seg : seg - 768;
        const int  head = segl >> 6;
        const int  Hcnt = isQ ? NHEAD : KVH;
        u16* outp = isQ ? Q : K;
        float bias[4];
        #pragma unroll
        for (int j = 0; j < 4; j++) {
            const int nl = segl + j * 16 + lo;
            bias[j] = isQ ? qb[nl] * QSCALE : kb[nl];
        }
        const float inv0 = exp2f(-(float)lo * ROPE_C);
        const float inv1 = exp2f(-(float)(16 + lo) * ROPE_C);
        int pmode;                             // pos dtype robustness
        if (pos[1] == 1)                         pmode = 0;
        else if (((const float*)pos)[1] == 1.0f) pmode = 1;
        else                                     pmode = 2;
        const int src0 = (hi << 4) | (lo >> 1);
        const int src1 = src0 | 8;
        const bool odd = (lo & 1) != 0;

        #pragma unroll
        for (int i = 0; i < 2; i++) {
            #pragma unroll
            for (int r = 0; r < 4; r++) {
                const float v0 = acc[i][0][r] + bias[0];
                const float v1 = acc[i][1][r] + bias[1];
                const float v2 = acc[i][2][r] + bias[2];
                const float v3 = acc[i][3][r] + bias[3];
                const float p0e = __shfl(v1, src0), p0o = __shfl(v3, src0);
                const float p1e = __shfl(v1, src1), p1o = __shfl(v3, src1);
                const float p2e = __shfl(v0, src0), p2o = __shfl(v2, src0);
                const float p3e = __shfl(v0, src1), p3o = __shfl(v2, src1);
                const float px0 = odd ? p0o : p0e;
                const float px1 = odd ? p1o : p1e;
                const float px2 = odd ? p2o : p2e;
                const float px3 = odd ? p3o : p3e;

                const int m = m0 + wr * 32 + i * 16 + hi * 4 + r;
                const int b = m >> 10, t = m & 1023;
                float pp;
                if (pmode == 0)      pp = (float)pos[t];
                else if (pmode == 1) pp = ((const float*)pos)[t];
                else                 pp = (float)pos[2 * t];

                const float a0 = pp * inv0, a1 = pp * inv1;
                const float sv0 = __sinf(a0), cv0 = __cosf(a0);
                const float sv1 = __sinf(a1), cv1 = __cosf(a1);
                const float o0 = v0 * cv0 - px0 * sv0;
                const float o1 = v1 * cv1 - px1 * sv1;
                const float o2 = v2 * cv0 + px2 * sv0;
                const float o3 = v3 * cv1 + px3 * sv1;

                u16* dst = outp + ((size_t)(b * Hcnt + head) * SEQ + t) * HD;
                dst[lo]      = f2bf(o0);
                dst[16 + lo] = f2bf(o1);
                dst[32 + lo] = f2bf(o2);
                dst[48 + lo] = f2bf(o3);
            }
        }
    }
}

// ======== output projection: ring-4 body (already single-batch at 3/CU) =====
__global__ __launch_bounds__(256, 2) void gemm_oproj(
    const u16* __restrict__ Ab, const u16* __restrict__ wt,
    const float* __restrict__ ob, float* __restrict__ outp)
{
    __shared__ __align__(16) u16 As[4][2048];
    __shared__ __align__(16) u16 Bs[4][4096];
    const int id = (blockIdx.x & 7) * 96 + (blockIdx.x >> 3);
    const int m0 = (id / 6) * 64;
    const int n0 = (id % 6) * 128;
    f32x4 acc[2][4];
    gemm64_body(Ab, wt, m0, n0, As, Bs, acc);

    const int tid = threadIdx.x;
    const int lane = tid & 63, wid = tid >> 6;
    const int wr = wid >> 1, wc = wid & 1;
    const int lo = lane & 15, hi = lane >> 4;

    #pragma unroll
    for (int j = 0; j < 4; j++) {
        const int n = n0 + wc * 64 + j * 16 + lo;
        const float bias = ob[n];
        #pragma unroll
        for (int i = 0; i < 2; i++) {
            #pragma unroll
            for (int r = 0; r < 4; r++) {
                const int m = m0 + wr * 32 + i * 16 + hi * 4 + r;
                outp[(size_t)m * DM + n] = acc[i][j][r] + bias;
            }
        }
    }
}

// ======== flash attention v9 (FROZEN, 43.6 us): row-split waves, LPT ========
__device__ __forceinline__ void strip_compute(
    const bf16x8& qf0, const bf16x8& qf1,
    const bf16x8& k0, const bf16x8& k1, const bf16x8& k2, const bf16x8& k3,
    const bf16x8* vv, bool diag, int msk0, int hi,
    float& m, float& l, f32x4* O)
{
    const f32x4 z = {0.f, 0.f, 0.f, 0.f};
    f32x4 a0 = z, a1 = z;
    __builtin_amdgcn_s_setprio(1);
    a0 = __builtin_amdgcn_mfma_f32_16x16x32_bf16(k0, qf0, a0, 0, 0, 0);
    a0 = __builtin_amdgcn_mfma_f32_16x16x32_bf16(k1, qf1, a0, 0, 0, 0);
    a1 = __builtin_amdgcn_mfma_f32_16x16x32_bf16(k2, qf0, a1, 0, 0, 0);
    a1 = __builtin_amdgcn_mfma_f32_16x16x32_bf16(k3, qf1, a1, 0, 0, 0);
    __builtin_amdgcn_s_setprio(0);

    float sc[8];
    #pragma unroll
    for (int e = 0; e < 8; ++e)
        sc[e] = (e < 4) ? a0[e & 3] : a1[e & 3];
    if (diag) {
        #pragma unroll
        for (int e = 0; e < 8; ++e) {
            const int srel = ((e >> 2) << 4) + (hi << 2) + (e & 3);
            if (srel > msk0) sc[e] = -3.0e38f;
        }
    }
    float pm = sc[0];
    #pragma unroll
    for (int e = 1; e < 8; ++e) pm = fmaxf(pm, sc[e]);

    if (!__all(pm - m <= 8.0f)) {            // defer-max (per-lane == per-row)
        float pr = fmaxf(pm, __shfl_xor(pm, 16));
        pr = fmaxf(pr, __shfl_xor(pr, 32));
        const float mn = fmaxf(m, pr);
        const float f = exp2f(m - mn);       // first tile: m=-3e38 -> f=0
        l *= f;
        #pragma unroll
        for (int r = 0; r < 4; ++r) {
            const float fr = __shfl(f, hi * 4 + r);
            #pragma unroll
            for (int dj = 0; dj < 4; ++dj) O[dj][r] *= fr;
        }
        m = mn;
    }

    union { u16 u[8]; bf16x8 v; } pu;
    float ps = 0.f;
    #pragma unroll
    for (int e = 0; e < 8; ++e) {
        const float p = exp2f(sc[e] - m);    // bounded by 2^8
        ps += p;
        pu.u[e] = f2bf(p);
    }
    l += ps;                                  // per-lane partial

    __builtin_amdgcn_s_setprio(1);
    #pragma unroll
    for (int dj = 0; dj < 4; ++dj)
        O[dj] = __builtin_amdgcn_mfma_f32_16x16x32_bf16(pu.v, vv[dj], O[dj], 0, 0, 0);
    __builtin_amdgcn_s_setprio(0);
}

__global__ __launch_bounds__(256, 4) void attn_mfma(
    const u16* __restrict__ Q, const u16* __restrict__ K,
    const u16* __restrict__ Vt, u16* __restrict__ outp)
{
    __shared__ __align__(16) u16 Ks[4][2048];   // ring-4: 32 s x 64 d, swizzled
    __shared__ __align__(16) u16 Vs[4][2048];   // ring-4: 64 d x 32 s, permuted

    const int blk = blockIdx.x;                  // 1536 = 8b*12h*16a
    const int xcd = blk & 7;
    const int jj  = blk >> 3;                    // 0..191
    const int bg  = (xcd << 2) + (jj & 3);       // 0..31
    const int rh  = jj >> 2;                     // 0..47
    const int a   = 15 - rh / 3;                 // q-block, DESCENDING (LPT)
    const int hl  = rh % 3;
    const int b   = bg >> 2, g = bg & 3;
    const int h   = g * REP + hl;

    const int wid  = threadIdx.x >> 6;
    const int lane = threadIdx.x & 63;
    const int lo = lane & 15, hi = lane >> 4;

    const int w    = (a << 2) + wid;             // strip 0..63 (16 q-rows)
    const int q0   = w << 4;
    const int dT   = w >> 1;                     // last tile for this strip
    const int msk0 = lo + ((w & 1) << 4);
    const int nstT = (a << 1) + 2;               // block trip count (= max dT+1)

    const u16* Kp = K  + (size_t)(b * KVH + g) * SEQ * HD;
    const u16* Vp = Vt + (size_t)(b * KVH + g) * SEQ * HD;   // [d][s]

    const int jK = (wid << 6) + lane;
    const int sKoff = (jK ^ ((jK >> 3) & 7)) << 3;           // u16 offset
    int vsoff[4];
    #pragma unroll
    for (int q = 0; q < 4; ++q) {
        const int dw  = (wid << 8) + (q << 6) + lane;
        const int R   = dw >> 4;
        const int wd  = dw & 15;
        const int hpl = (wd >> 2) ^ ((R >> 1) & 3);
        vsoff[q] = (R << 10) + (hpl << 2) + (((wd >> 1) & 1) << 4) + ((wd & 1) << 1);
    }

    const u16* Qp = Q + ((size_t)(b * NHEAD + h) * SEQ + q0) * HD;
    const bf16x8 qf0 = *(const bf16x8*)&Qp[(size_t)lo * HD + hi * 8];
    const bf16x8 qf1 = *(const bf16x8*)&Qp[(size_t)lo * HD + 32 + hi * 8];

    const f32x4 z = {0.f, 0.f, 0.f, 0.f};
    f32x4 O[4];
    #pragma unroll
    for (int dj = 0; dj < 4; ++dj) O[dj] = z;
    float m = -3.0e38f, l = 0.f;

    #define STAGE(st_, sl_) do {                                              \
        const int s0_ = (st_) << 5;                                           \
        __builtin_amdgcn_global_load_lds(                                     \
            (gu32_c*)(Kp + (s0_ << 6) + sKoff),                               \
            (su32*)&Ks[sl_][wid << 9], 16, 0, 0);                             \
        _Pragma("unroll")                                                     \
        for (int q_ = 0; q_ < 4; ++q_)                                        \
            __builtin_amdgcn_global_load_lds(                                 \
                (gu32_c*)(Vp + s0_ + vsoff[q_]),                              \
                (su32*)&Vs[sl_][(wid << 9) + (q_ << 7)], 4, 0, 0);            \
    } while (0)

    STAGE(0, 0);
    STAGE(1, 1);

    const int xorK = lo & 7;
    for (int st = 0; st < nstT; ++st) {
        const int s2 = (st + 2 < nstT) ? st + 2 : nstT - 1;  // clamp: never read
        STAGE(s2, (st + 2) & 3);
        asm volatile("s_waitcnt vmcnt(10)" ::: "memory");
        __builtin_amdgcn_s_barrier();
        __builtin_amdgcn_sched_barrier(0);

        if (st <= dT) {
            const int sl = st & 3;
            const u16* kb_ = Ks[sl];
            const bf16x8 k0 = *(const bf16x8*)&kb_[((lo << 3) + (hi ^ xorK)) << 3];
            const bf16x8 k1 = *(const bf16x8*)&kb_[((lo << 3) + ((4 + hi) ^ xorK)) << 3];
            const bf16x8 k2 = *(const bf16x8*)&kb_[(((16 + lo) << 3) + (hi ^ xorK)) << 3];
            const bf16x8 k3 = *(const bf16x8*)&kb_[(((16 + lo) << 3) + ((4 + hi) ^ xorK)) << 3];
            bf16x8 vv[4];
            #pragma unroll
            for (int dj = 0; dj < 4; ++dj) {
                const int R = dj * 16 + lo;
                vv[dj] = *(const bf16x8*)&Vs[sl][(R << 5) + ((hi ^ ((R >> 1) & 3)) << 3)];
            }
            strip_compute(qf0, qf1, k0, k1, k2, k3, vv, st == dT, msk0, hi, m, l, O);
        }
    }
    #undef STAGE

    // epilogue: reduce per-lane l across hi-groups, then per-row store
    l += __shfl_xor(l, 16); l += __shfl_xor(l, 32);
    #pragma unroll
    for (int r = 0; r < 4; ++r) {
        const float li = 1.0f / fmaxf(__shfl(l, hi * 4 + r), 1e-37f);
        const int t = q0 + hi * 4 + r;
        #pragma unroll
        for (int dj = 0; dj < 4; ++dj)
            outp[((size_t)(b * SEQ + t)) * DM + h * HD + dj * 16 + lo] = f2bf(O[dj][r] * li);
    }
}

extern "C" void kernel_launch(void* const* d_in, const int* in_sizes, int n_in,
                              void* d_out, int out_size, void* d_ws, size_t ws_size,
                              hipStream_t stream) {
    const float* x   = (const float*)d_in[0];
    const int*   pos = (const int*)d_in[1];
    const float* qw  = (const float*)d_in[2];
    const float* qb  = (const float*)d_in[3];
    const float* kw  = (const float*)d_in[4];
    const float* kb  = (const float*)d_in[5];
    const float* vw  = (const float*)d_in[6];
    const float* vb  = (const float*)d_in[7];
    const float* ow  = (const float*)d_in[8];
    const float* ob  = (const float*)d_in[9];
    float* out = (float*)d_out;                 // OUTPUT IS FP32

    u16* xb    = (u16*)d_ws;                                    // 6291456
    u16* Wqkvt = xb    + (size_t)8192 * DM;                     //  983040
    u16* Wot   = Wqkvt + (size_t)1280 * DM;                     //  589824
    u16* Qbuf  = Wot   + (size_t)DM * DM;                       // 6291456 (rope'd)
    u16* Kbuf  = Qbuf  + (size_t)BATCH * NHEAD * SEQ * HD;      // 2097152 (rope'd)
    u16* Vtb   = Kbuf  + (size_t)BATCH * KVH * SEQ * HD;        // 2097152 [b,g,d,s]
    u16* attn  = xb;     // alias: xb dead after gemm_qkv

    const int NCVT = 8192 * DM / 4 + 1280 * DM + DM * DM;
    cvt_all<<<(NCVT + 255) / 256, 256, 0, stream>>>(x, qw, kw, vw, ow, xb, Wqkvt, Wot);

    gemm_qkv<<<1280, 256, 0, stream>>>(xb, Wqkvt, qb, kb, vb, pos, Qbuf, Kbuf, Vtb);

    attn_mfma<<<1536, 256, 0, stream>>>(Qbuf, Kbuf, Vtb, attn);

    gemm_oproj<<<768, 256, 0, stream>>>(attn, Wot, ob, out);
}

// Round 17
// 188.539 us; speedup vs baseline: 1.1447x; 1.0066x over previous
//
#include <hip/hip_runtime.h>
#include <hip/hip_bf16.h>
#include <math.h>

#define BATCH 8
#define SEQ   1024
#define DM    768
#define NHEAD 12
#define KVH   4
#define HD    64
#define REP   3

// softmax scale folded into Q weights, exp2 domain: 0.125 * log2(e)
#define QSCALE 0.18033688011112042f
// RoPE: inv_freq(j) = exp2(-j * LOG2_BASE_OVER_HALF / 32), j in [0,32)
#define ROPE_C (13.287712379549449f / 32.0f)

typedef unsigned short u16;
typedef __attribute__((ext_vector_type(8))) __bf16 bf16x8;
typedef __attribute__((ext_vector_type(4))) float f32x4;
typedef __attribute__((ext_vector_type(4))) unsigned int u32x4;
typedef __attribute__((address_space(1))) const unsigned int gu32_c;
typedef __attribute__((address_space(3))) unsigned int su32;

// RTNE fp32 -> bf16 (finite values)
__device__ __forceinline__ u16 f2bf(float f) {
    unsigned int u = __float_as_uint(f);
    u += 0x7fffu + ((u >> 16) & 1u);
    return (u16)(u >> 16);
}

// ======== fused converts: x->bf16, Wqkv^T (Q cols pre-scaled), Wo^T ==========
__global__ __launch_bounds__(256) void cvt_all(
    const float* __restrict__ x,
    const float* __restrict__ qw, const float* __restrict__ kw,
    const float* __restrict__ vw, const float* __restrict__ ow,
    u16* __restrict__ xb, u16* __restrict__ wqkvt, u16* __restrict__ wot)
{
    const int NX = 8192 * DM / 4;          // float4 items
    const int NW = 1280 * DM;
    const int NO = DM * DM;
    const int i = blockIdx.x * 256 + threadIdx.x;
    if (i < NX) {
        const float4 v = ((const float4*)x)[i];
        ushort4 r;
        r.x = f2bf(v.x); r.y = f2bf(v.y); r.z = f2bf(v.z); r.w = f2bf(v.w);
        ((ushort4*)xb)[i] = r;
    } else if (i < NX + NW) {
        const int idx = i - NX;                // idx = n*768 + k
        const int k = idx % DM;
        const int n = idx / DM;
        float v;
        if (n < 768)       v = qw[(size_t)k * 768 + n] * QSCALE;
        else if (n < 1024) v = kw[(size_t)k * 256 + (n - 768)];
        else               v = vw[(size_t)k * 256 + (n - 1024)];
        wqkvt[idx] = f2bf(v);
    } else if (i < NX + NW + NO) {
        const int idx = i - NX - NW;
        const int k = idx % DM;
        const int n = idx / DM;
        wot[idx] = f2bf(ow[(size_t)k * DM + n]);
    }
}

// ======== 64x128 GEMM body v2: ring-2, depth-1 prefetch, 2 barriers =========
// LDS 24KB -> 6 blocks/CU: qkv's 1280 blocks (5/CU) in ONE batch.
// Trailing barrier = WAR protection for slot (kt+1)&1.
__device__ __forceinline__ void gemm64_body2(
    const u16* __restrict__ A, const u16* __restrict__ B,
    int m0, int n0, u16 (*As)[2048], u16 (*Bs)[4096], f32x4 acc[2][4])
{
    const int tid  = threadIdx.x;
    const int lane = tid & 63;
    const int wid  = tid >> 6;
    const int wr = wid >> 1, wc = wid & 1;
    const int lo = lane & 15, hi = lane >> 4;

    const f32x4 z = {0.f, 0.f, 0.f, 0.f};
    #pragma unroll
    for (int i = 0; i < 2; i++)
        #pragma unroll
        for (int j = 0; j < 4; j++)
            acc[i][j] = z;

    const int NT = DM / 32;                   // 24 K-steps
    const int rowA = tid >> 2;
    const int colA = (tid & 3) << 3;

    #define STAGE_G(kt_, sl_) do {                                            \
        __builtin_amdgcn_global_load_lds(                                     \
            (gu32_c*)&A[(size_t)(m0 + rowA) * DM + (kt_) * 32 + colA],        \
            (su32*)&As[sl_][wid << 9], 16, 0, 0);                             \
        _Pragma("unroll")                                                     \
        for (int r_ = 0; r_ < 2; ++r_) {                                      \
            const int idx_  = r_ * 256 + tid;                                 \
            const int row_  = idx_ >> 2;                                      \
            const int col_  = (idx_ & 3) << 3;                                \
            const int base_ = (r_ * 256 + wid * 64) * 8;                      \
            __builtin_amdgcn_global_load_lds(                                 \
                (gu32_c*)&B[(size_t)(n0 + row_) * DM + (kt_) * 32 + col_],    \
                (su32*)&Bs[sl_][base_], 16, 0, 0);                            \
        }                                                                     \
    } while (0)

    STAGE_G(0, 0);

    for (int kt = 0; kt < NT; ++kt) {
        const int k1 = (kt + 1 < NT) ? kt + 1 : NT - 1;   // clamp: never read
        STAGE_G(k1, (kt + 1) & 1);
        asm volatile("s_waitcnt vmcnt(3)" ::: "memory");
        __builtin_amdgcn_s_barrier();
        __builtin_amdgcn_sched_barrier(0);

        const int sl = kt & 1;
        bf16x8 af[2], bfr[4];
        #pragma unroll
        for (int i = 0; i < 2; i++) af[i]  = *(const bf16x8*)&As[sl][(wr * 32 + i * 16 + lo) * 32 + hi * 8];
        #pragma unroll
        for (int j = 0; j < 4; j++) bfr[j] = *(const bf16x8*)&Bs[sl][(wc * 64 + j * 16 + lo) * 32 + hi * 8];
        #pragma unroll
        for (int i = 0; i < 2; i++)
            #pragma unroll
            for (int j = 0; j < 4; j++)
                acc[i][j] = __builtin_amdgcn_mfma_f32_16x16x32_bf16(af[i], bfr[j], acc[i][j], 0, 0, 0);

        __builtin_amdgcn_s_barrier();         // WAR: protect slot before re-stage
    }
    #undef STAGE_G
}

// ======== 64x128 GEMM body: ring-4 counted-vmcnt (r9-proven, for oproj) =====
__device__ __forceinline__ void gemm64_body(
    const u16* __restrict__ A, const u16* __restrict__ B,
    int m0, int n0, u16 (*As)[2048], u16 (*Bs)[4096], f32x4 acc[2][4])
{
    const int tid  = threadIdx.x;
    const int lane = tid & 63;
    const int wid  = tid >> 6;
    const int wr = wid >> 1, wc = wid & 1;
    const int lo = lane & 15, hi = lane >> 4;

    const f32x4 z = {0.f, 0.f, 0.f, 0.f};
    #pragma unroll
    for (int i = 0; i < 2; i++)
        #pragma unroll
        for (int j = 0; j < 4; j++)
            acc[i][j] = z;

    const int NT = DM / 32;                   // 24 K-steps
    const int rowA = tid >> 2;
    const int colA = (tid & 3) << 3;

    #define STAGE_G(kt_, sl_) do {                                            \
        __builtin_amdgcn_global_load_lds(                                     \
            (gu32_c*)&A[(size_t)(m0 + rowA) * DM + (kt_) * 32 + colA],        \
            (su32*)&As[sl_][wid << 9], 16, 0, 0);                             \
        _Pragma("unroll")                                                     \
        for (int r_ = 0; r_ < 2; ++r_) {                                      \
            const int idx_  = r_ * 256 + tid;                                 \
            const int row_  = idx_ >> 2;                                      \
            const int col_  = (idx_ & 3) << 3;                                \
            const int base_ = (r_ * 256 + wid * 64) * 8;                      \
            __builtin_amdgcn_global_load_lds(                                 \
                (gu32_c*)&B[(size_t)(n0 + row_) * DM + (kt_) * 32 + col_],    \
                (su32*)&Bs[sl_][base_], 16, 0, 0);                            \
        }                                                                     \
    } while (0)

    STAGE_G(0, 0);
    STAGE_G(1, 1);

    for (int kt = 0; kt < NT; ++kt) {
        const int k2 = (kt + 2 < NT) ? kt + 2 : NT - 1;   // clamp: never read
        STAGE_G(k2, (kt + 2) & 3);
        asm volatile("s_waitcnt vmcnt(6)" ::: "memory");
        __builtin_amdgcn_s_barrier();
        __builtin_amdgcn_sched_barrier(0);

        const int sl = kt & 3;
        bf16x8 af[2], bfr[4];
        #pragma unroll
        for (int i = 0; i < 2; i++) af[i]  = *(const bf16x8*)&As[sl][(wr * 32 + i * 16 + lo) * 32 + hi * 8];
        #pragma unroll
        for (int j = 0; j < 4; j++) bfr[j] = *(const bf16x8*)&Bs[sl][(wc * 64 + j * 16 + lo) * 32 + hi * 8];
        #pragma unroll
        for (int i = 0; i < 2; i++)
            #pragma unroll
            for (int j = 0; j < 4; j++)
                acc[i][j] = __builtin_amdgcn_mfma_f32_16x16x32_bf16(af[i], bfr[j], acc[i][j], 0, 0, 0);
    }
    #undef STAGE_G
}

// ======== QKV projection with FUSED RoPE (ring-2 body: 24KB LDS, 5/CU) ======
__global__ __launch_bounds__(256, 2) void gemm_qkv(
    const u16* __restrict__ xb, const u16* __restrict__ wt,
    const float* __restrict__ qb, const float* __restrict__ kb,
    const float* __restrict__ vb, const int* __restrict__ pos,
    u16* __restrict__ Q, u16* __restrict__ K, u16* __restrict__ Vt)
{
    __shared__ __align__(16) u16 As[2][2048];
    __shared__ __align__(16) u16 Bs[2][4096];
    const int id = (blockIdx.x & 7) * 160 + (blockIdx.x >> 3);
    const int m0 = (id / 10) * 64;
    const int n0 = (id % 10) * 128;
    f32x4 acc[2][4];
    gemm64_body2(xb, wt, m0, n0, As, Bs, acc);

    const int tid = threadIdx.x;
    const int lane = tid & 63, wid = tid >> 6;
    const int wr = wid >> 1, wc = wid & 1;
    const int lo = lane & 15, hi = lane >> 4;

    const int seg = n0 + wc * 64;            // wave-uniform, 64-aligned

    if (seg >= 1024) {
        // V: [b,g,d,t], ushort4 stores (4 consecutive t)
        #pragma unroll
        for (int j = 0; j < 4; j++) {
            const int nl = seg - 1024 + j * 16 + lo;
            const float bias = vb[nl];
            const int head = nl >> 6, d = nl & 63;
            #pragma unroll
            for (int i = 0; i < 2; i++) {
                ushort4 vs;
                vs.x = f2bf(acc[i][j][0] + bias);
                vs.y = f2bf(acc[i][j][1] + bias);
                vs.z = f2bf(acc[i][j][2] + bias);
                vs.w = f2bf(acc[i][j][3] + bias);
                const int m = m0 + wr * 32 + i * 16 + hi * 4;
                const int b = m >> 10, t = m & 1023;
                *(ushort4*)&Vt[(((size_t)(b * KVH + head)) * HD + d) * SEQ + t] = vs;
            }
        }
    } else {
        const bool isQ = seg < 768;
        const int  segl = isQ ? seg : seg - 768;
        const int  head = segl >> 6;
        const int  Hcnt = isQ ? NHEAD : KVH;
        u16* outp = isQ ? Q : K;
        float bias[4];
        #pragma unroll
        for (int j = 0; j < 4; j++) {
            const int nl = segl + j * 16 + lo;
            bias[j] = isQ ? qb[nl] * QSCALE : kb[nl];
        }
        const float inv0 = exp2f(-(float)lo * ROPE_C);
        const float inv1 = exp2f(-(float)(16 + lo) * ROPE_C);
        int pmode;                             // pos dtype robustness
        if (pos[1] == 1)                         pmode = 0;
        else if (((const float*)pos)[1] == 1.0f) pmode = 1;
        else                                     pmode = 2;
        const int src0 = (hi << 4) | (lo >> 1);
        const int src1 = src0 | 8;
        const bool odd = (lo & 1) != 0;

        #pragma unroll
        for (int i = 0; i < 2; i++) {
            #pragma unroll
            for (int r = 0; r < 4; r++) {
                const float v0 = acc[i][0][r] + bias[0];
                const float v1 = acc[i][1][r] + bias[1];
                const float v2 = acc[i][2][r] + bias[2];
                const float v3 = acc[i][3][r] + bias[3];
                const float p0e = __shfl(v1, src0), p0o = __shfl(v3, src0);
                const float p1e = __shfl(v1, src1), p1o = __shfl(v3, src1);
                const float p2e = __shfl(v0, src0), p2o = __shfl(v2, src0);
                const float p3e = __shfl(v0, src1), p3o = __shfl(v2, src1);
                const float px0 = odd ? p0o : p0e;
                const float px1 = odd ? p1o : p1e;
                const float px2 = odd ? p2o : p2e;
                const float px3 = odd ? p3o : p3e;

                const int m = m0 + wr * 32 + i * 16 + hi * 4 + r;
                const int b = m >> 10, t = m & 1023;
                float pp;
                if (pmode == 0)      pp = (float)pos[t];
                else if (pmode == 1) pp = ((const float*)pos)[t];
                else                 pp = (float)pos[2 * t];

                const float a0 = pp * inv0, a1 = pp * inv1;
                const float sv0 = __sinf(a0), cv0 = __cosf(a0);
                const float sv1 = __sinf(a1), cv1 = __cosf(a1);
                const float o0 = v0 * cv0 - px0 * sv0;
                const float o1 = v1 * cv1 - px1 * sv1;
                const float o2 = v2 * cv0 + px2 * sv0;
                const float o3 = v3 * cv1 + px3 * sv1;

                u16* dst = outp + ((size_t)(b * Hcnt + head) * SEQ + t) * HD;
                dst[lo]      = f2bf(o0);
                dst[16 + lo] = f2bf(o1);
                dst[32 + lo] = f2bf(o2);
                dst[48 + lo] = f2bf(o3);
            }
        }
    }
}

// ======== output projection: ring-4 body (grid 768 = 3/CU, single batch) ====
__global__ __launch_bounds__(256, 2) void gemm_oproj(
    const u16* __restrict__ Ab, const u16* __restrict__ wt,
    const float* __restrict__ ob, float* __restrict__ outp)
{
    __shared__ __align__(16) u16 As[4][2048];
    __shared__ __align__(16) u16 Bs[4][4096];
    const int id = (blockIdx.x & 7) * 96 + (blockIdx.x >> 3);
    const int m0 = (id / 6) * 64;
    const int n0 = (id % 6) * 128;
    f32x4 acc[2][4];
    gemm64_body(Ab, wt, m0, n0, As, Bs, acc);

    const int tid = threadIdx.x;
    const int lane = tid & 63, wid = tid >> 6;
    const int wr = wid >> 1, wc = wid & 1;
    const int lo = lane & 15, hi = lane >> 4;

    #pragma unroll
    for (int j = 0; j < 4; j++) {
        const int n = n0 + wc * 64 + j * 16 + lo;
        const float bias = ob[n];
        #pragma unroll
        for (int i = 0; i < 2; i++) {
            #pragma unroll
            for (int r = 0; r < 4; r++) {
                const int m = m0 + wr * 32 + i * 16 + hi * 4 + r;
                outp[(size_t)m * DM + n] = acc[i][j][r] + bias;
            }
        }
    }
}

// ======== flash attention v11: v9 structure + ring-2 LDS (16KB, 6/CU) =======
// v9's ring-4 (32KB) capped residency at 5 blocks/CU but grid 1536 needs
// 6/CU -> 1.2 dispatch batches (tail).  Ring-2 + depth-1 + trailing barrier
// (r16-proven in qkv) -> 16KB -> all 1536 blocks co-resident, single batch.
// vmcnt(5): the 5 loads of STAGE(st+1) stay in flight; drains STAGE(st).
__device__ __forceinline__ void strip_compute(
    const bf16x8& qf0, const bf16x8& qf1,
    const bf16x8& k0, const bf16x8& k1, const bf16x8& k2, const bf16x8& k3,
    const bf16x8* vv, bool diag, int msk0, int hi,
    float& m, float& l, f32x4* O)
{
    const f32x4 z = {0.f, 0.f, 0.f, 0.f};
    f32x4 a0 = z, a1 = z;
    __builtin_amdgcn_s_setprio(1);
    a0 = __builtin_amdgcn_mfma_f32_16x16x32_bf16(k0, qf0, a0, 0, 0, 0);
    a0 = __builtin_amdgcn_mfma_f32_16x16x32_bf16(k1, qf1, a0, 0, 0, 0);
    a1 = __builtin_amdgcn_mfma_f32_16x16x32_bf16(k2, qf0, a1, 0, 0, 0);
    a1 = __builtin_amdgcn_mfma_f32_16x16x32_bf16(k3, qf1, a1, 0, 0, 0);
    __builtin_amdgcn_s_setprio(0);

    float sc[8];
    #pragma unroll
    for (int e = 0; e < 8; ++e)
        sc[e] = (e < 4) ? a0[e & 3] : a1[e & 3];
    if (diag) {
        #pragma unroll
        for (int e = 0; e < 8; ++e) {
            const int srel = ((e >> 2) << 4) + (hi << 2) + (e & 3);
            if (srel > msk0) sc[e] = -3.0e38f;
        }
    }
    float pm = sc[0];
    #pragma unroll
    for (int e = 1; e < 8; ++e) pm = fmaxf(pm, sc[e]);

    if (!__all(pm - m <= 8.0f)) {            // defer-max (per-lane == per-row)
        float pr = fmaxf(pm, __shfl_xor(pm, 16));
        pr = fmaxf(pr, __shfl_xor(pr, 32));
        const float mn = fmaxf(m, pr);
        const float f = exp2f(m - mn);       // first tile: m=-3e38 -> f=0
        l *= f;
        #pragma unroll
        for (int r = 0; r < 4; ++r) {
            const float fr = __shfl(f, hi * 4 + r);
            #pragma unroll
            for (int dj = 0; dj < 4; ++dj) O[dj][r] *= fr;
        }
        m = mn;
    }

    union { u16 u[8]; bf16x8 v; } pu;
    float ps = 0.f;
    #pragma unroll
    for (int e = 0; e < 8; ++e) {
        const float p = exp2f(sc[e] - m);    // bounded by 2^8
        ps += p;
        pu.u[e] = f2bf(p);
    }
    l += ps;                                  // per-lane partial

    __builtin_amdgcn_s_setprio(1);
    #pragma unroll
    for (int dj = 0; dj < 4; ++dj)
        O[dj] = __builtin_amdgcn_mfma_f32_16x16x32_bf16(pu.v, vv[dj], O[dj], 0, 0, 0);
    __builtin_amdgcn_s_setprio(0);
}

__global__ __launch_bounds__(256, 6) void attn_mfma(
    const u16* __restrict__ Q, const u16* __restrict__ K,
    const u16* __restrict__ Vt, u16* __restrict__ outp)
{
    __shared__ __align__(16) u16 Ks[2][2048];   // ring-2: 32 s x 64 d, swizzled
    __shared__ __align__(16) u16 Vs[2][2048];   // ring-2: 64 d x 32 s, permuted

    const int blk = blockIdx.x;                  // 1536 = 8b*12h*16a
    const int xcd = blk & 7;
    const int jj  = blk >> 3;                    // 0..191
    const int bg  = (xcd << 2) + (jj & 3);       // 0..31
    const int rh  = jj >> 2;                     // 0..47
    const int a   = 15 - rh / 3;                 // q-block, DESCENDING (LPT)
    const int hl  = rh % 3;
    const int b   = bg >> 2, g = bg & 3;
    const int h   = g * REP + hl;

    const int wid  = threadIdx.x >> 6;
    const int lane = threadIdx.x & 63;
    const int lo = lane & 15, hi = lane >> 4;

    const int w    = (a << 2) + wid;             // strip 0..63 (16 q-rows)
    const int q0   = w << 4;
    const int dT   = w >> 1;                     // last tile for this strip
    const int msk0 = lo + ((w & 1) << 4);
    const int nstT = (a << 1) + 2;               // block trip count (= max dT+1)

    const u16* Kp = K  + (size_t)(b * KVH + g) * SEQ * HD;
    const u16* Vp = Vt + (size_t)(b * KVH + g) * SEQ * HD;   // [d][s]

    const int jK = (wid << 6) + lane;
    const int sKoff = (jK ^ ((jK >> 3) & 7)) << 3;           // u16 offset
    int vsoff[4];
    #pragma unroll
    for (int q = 0; q < 4; ++q) {
        const int dw  = (wid << 8) + (q << 6) + lane;
        const int R   = dw >> 4;
        const int wd  = dw & 15;
        const int hpl = (wd >> 2) ^ ((R >> 1) & 3);
        vsoff[q] = (R << 10) + (hpl << 2) + (((wd >> 1) & 1) << 4) + ((wd & 1) << 1);
    }

    const u16* Qp = Q + ((size_t)(b * NHEAD + h) * SEQ + q0) * HD;
    const bf16x8 qf0 = *(const bf16x8*)&Qp[(size_t)lo * HD + hi * 8];
    const bf16x8 qf1 = *(const bf16x8*)&Qp[(size_t)lo * HD + 32 + hi * 8];

    const f32x4 z = {0.f, 0.f, 0.f, 0.f};
    f32x4 O[4];
    #pragma unroll
    for (int dj = 0; dj < 4; ++dj) O[dj] = z;
    float m = -3.0e38f, l = 0.f;

    #define STAGE(st_, sl_) do {                                              \
        const int s0_ = (st_) << 5;                                           \
        __builtin_amdgcn_global_load_lds(                                     \
            (gu32_c*)(Kp + (s0_ << 6) + sKoff),                               \
            (su32*)&Ks[sl_][wid << 9], 16, 0, 0);                             \
        _Pragma("unroll")                                                     \
        for (int q_ = 0; q_ < 4; ++q_)                                        \
            __builtin_amdgcn_global_load_lds(                                 \
                (gu32_c*)(Vp + s0_ + vsoff[q_]),                              \
                (su32*)&Vs[sl_][(wid << 9) + (q_ << 7)], 4, 0, 0);            \
    } while (0)

    STAGE(0, 0);

    const int xorK = lo & 7;
    for (int st = 0; st < nstT; ++st) {
        const int s1 = (st + 1 < nstT) ? st + 1 : nstT - 1;  // clamp: never read
        STAGE(s1, (st + 1) & 1);
        asm volatile("s_waitcnt vmcnt(5)" ::: "memory");
        __builtin_amdgcn_s_barrier();
        __builtin_amdgcn_sched_barrier(0);

        if (st <= dT) {
            const int sl = st & 1;
            const u16* kb_ = Ks[sl];
            const bf16x8 k0 = *(const bf16x8*)&kb_[((lo << 3) + (hi ^ xorK)) << 3];
            const bf16x8 k1 = *(const bf16x8*)&kb_[((lo << 3) + ((4 + hi) ^ xorK)) << 3];
            const bf16x8 k2 = *(const bf16x8*)&kb_[(((16 + lo) << 3) + (hi ^ xorK)) << 3];
            const bf16x8 k3 = *(const bf16x8*)&kb_[(((16 + lo) << 3) + ((4 + hi) ^ xorK)) << 3];
            bf16x8 vv[4];
            #pragma unroll
            for (int dj = 0; dj < 4; ++dj) {
                const int R = dj * 16 + lo;
                vv[dj] = *(const bf16x8*)&Vs[sl][(R << 5) + ((hi ^ ((R >> 1) & 3)) << 3)];
            }
            strip_compute(qf0, qf1, k0, k1, k2, k3, vv, st == dT, msk0, hi, m, l, O);
        }
        __builtin_amdgcn_s_barrier();         // WAR: protect slot before re-stage
    }
    #undef STAGE

    // epilogue: reduce per-lane l across hi-groups, then per-row store
    l += __shfl_xor(l, 16); l += __shfl_xor(l, 32);
    #pragma unroll
    for (int r = 0; r < 4; ++r) {
        const float li = 1.0f / fmaxf(__shfl(l, hi * 4 + r), 1e-37f);
        const int t = q0 + hi * 4 + r;
        #pragma unroll
        for (int dj = 0; dj < 4; ++dj)
            outp[((size_t)(b * SEQ + t)) * DM + h * HD + dj * 16 + lo] = f2bf(O[dj][r] * li);
    }
}

extern "C" void kernel_launch(void* const* d_in, const int* in_sizes, int n_in,
                              void* d_out, int out_size, void* d_ws, size_t ws_size,
                              hipStream_t stream) {
    const float* x   = (const float*)d_in[0];
    const int*   pos = (const int*)d_in[1];
    const float* qw  = (const float*)d_in[2];
    const float* qb  = (const float*)d_in[3];
    const float* kw  = (const float*)d_in[4];
    const float* kb  = (const float*)d_in[5];
    const float* vw  = (const float*)d_in[6];
    const float* vb  = (const float*)d_in[7];
    const float* ow  = (const float*)d_in[8];
    const float* ob  = (const float*)d_in[9];
    float* out = (float*)d_out;                 // OUTPUT IS FP32

    u16* xb    = (u16*)d_ws;                                    // 6291456
    u16* Wqkvt = xb    + (size_t)8192 * DM;                     //  983040
    u16* Wot   = Wqkvt + (size_t)1280 * DM;                     //  589824
    u16* Qbuf  = Wot   + (size_t)DM * DM;                       // 6291456 (rope'd)
    u16* Kbuf  = Qbuf  + (size_t)BATCH * NHEAD * SEQ * HD;      // 2097152 (rope'd)
    u16* Vtb   = Kbuf  + (size_t)BATCH * KVH * SEQ * HD;        // 2097152 [b,g,d,s]
    u16* attn  = xb;     // alias: xb dead after gemm_qkv

    const int NCVT = 8192 * DM / 4 + 1280 * DM + DM * DM;
    cvt_all<<<(NCVT + 255) / 256, 256, 0, stream>>>(x, qw, kw, vw, ow, xb, Wqkvt, Wot);

    gemm_qkv<<<1280, 256, 0, stream>>>(xb, Wqkvt, qb, kb, vb, pos, Qbuf, Kbuf, Vtb);

    attn_mfma<<<1536, 256, 0, stream>>>(Qbuf, Kbuf, Vtb, attn);

    gemm_oproj<<<768, 256, 0, stream>>>(attn, Wot, ob, out);
}

// Round 18
// 187.881 us; speedup vs baseline: 1.1487x; 1.0035x over previous
//
#include <hip/hip_runtime.h>
#include <hip/hip_bf16.h>
#include <math.h>

#define BATCH 8
#define SEQ   1024
#define DM    768
#define NHEAD 12
#define KVH   4
#define HD    64
#define REP   3

// softmax scale folded into Q weights, exp2 domain: 0.125 * log2(e)
#define QSCALE 0.18033688011112042f
// RoPE: inv_freq(j) = exp2(-j * LOG2_BASE_OVER_HALF / 32), j in [0,32)
#define ROPE_C (13.287712379549449f / 32.0f)

typedef unsigned short u16;
typedef __attribute__((ext_vector_type(8))) __bf16 bf16x8;
typedef __attribute__((ext_vector_type(4))) float f32x4;
typedef __attribute__((ext_vector_type(4))) unsigned int u32x4;
typedef __attribute__((address_space(1))) const unsigned int gu32_c;
typedef __attribute__((address_space(3))) unsigned int su32;

// RTNE fp32 -> bf16 (finite values)
__device__ __forceinline__ u16 f2bf(float f) {
    unsigned int u = __float_as_uint(f);
    u += 0x7fffu + ((u >> 16) & 1u);
    return (u16)(u >> 16);
}

// ======== fused converts: x->bf16, Wqkv^T (Q cols pre-scaled), Wo^T ==========
__global__ __launch_bounds__(256) void cvt_all(
    const float* __restrict__ x,
    const float* __restrict__ qw, const float* __restrict__ kw,
    const float* __restrict__ vw, const float* __restrict__ ow,
    u16* __restrict__ xb, u16* __restrict__ wqkvt, u16* __restrict__ wot)
{
    const int NX = 8192 * DM / 4;          // float4 items
    const int NW = 1280 * DM;
    const int NO = DM * DM;
    const int i = blockIdx.x * 256 + threadIdx.x;
    if (i < NX) {
        const float4 v = ((const float4*)x)[i];
        ushort4 r;
        r.x = f2bf(v.x); r.y = f2bf(v.y); r.z = f2bf(v.z); r.w = f2bf(v.w);
        ((ushort4*)xb)[i] = r;
    } else if (i < NX + NW) {
        const int idx = i - NX;                // idx = n*768 + k
        const int k = idx % DM;
        const int n = idx / DM;
        float v;
        if (n < 768)       v = qw[(size_t)k * 768 + n] * QSCALE;
        else if (n < 1024) v = kw[(size_t)k * 256 + (n - 768)];
        else               v = vw[(size_t)k * 256 + (n - 1024)];
        wqkvt[idx] = f2bf(v);
    } else if (i < NX + NW + NO) {
        const int idx = i - NX - NW;
        const int k = idx % DM;
        const int n = idx / DM;
        wot[idx] = f2bf(ow[(size_t)k * DM + n]);
    }
}

// ======== 64x128 GEMM body v2: ring-2, depth-1 prefetch, 2 barriers =========
// LDS 24KB -> 6 blocks/CU: qkv's 1280 blocks (5/CU) in ONE batch.
// Trailing barrier = WAR protection for slot (kt+1)&1.
__device__ __forceinline__ void gemm64_body2(
    const u16* __restrict__ A, const u16* __restrict__ B,
    int m0, int n0, u16 (*As)[2048], u16 (*Bs)[4096], f32x4 acc[2][4])
{
    const int tid  = threadIdx.x;
    const int lane = tid & 63;
    const int wid  = tid >> 6;
    const int wr = wid >> 1, wc = wid & 1;
    const int lo = lane & 15, hi = lane >> 4;

    const f32x4 z = {0.f, 0.f, 0.f, 0.f};
    #pragma unroll
    for (int i = 0; i < 2; i++)
        #pragma unroll
        for (int j = 0; j < 4; j++)
            acc[i][j] = z;

    const int NT = DM / 32;                   // 24 K-steps
    const int rowA = tid >> 2;
    const int colA = (tid & 3) << 3;

    #define STAGE_G(kt_, sl_) do {                                            \
        __builtin_amdgcn_global_load_lds(                                     \
            (gu32_c*)&A[(size_t)(m0 + rowA) * DM + (kt_) * 32 + colA],        \
            (su32*)&As[sl_][wid << 9], 16, 0, 0);                             \
        _Pragma("unroll")                                                     \
        for (int r_ = 0; r_ < 2; ++r_) {                                      \
            const int idx_  = r_ * 256 + tid;                                 \
            const int row_  = idx_ >> 2;                                      \
            const int col_  = (idx_ & 3) << 3;                                \
            const int base_ = (r_ * 256 + wid * 64) * 8;                      \
            __builtin_amdgcn_global_load_lds(                                 \
                (gu32_c*)&B[(size_t)(n0 + row_) * DM + (kt_) * 32 + col_],    \
                (su32*)&Bs[sl_][base_], 16, 0, 0);                            \
        }                                                                     \
    } while (0)

    STAGE_G(0, 0);

    for (int kt = 0; kt < NT; ++kt) {
        const int k1 = (kt + 1 < NT) ? kt + 1 : NT - 1;   // clamp: never read
        STAGE_G(k1, (kt + 1) & 1);
        asm volatile("s_waitcnt vmcnt(3)" ::: "memory");
        __builtin_amdgcn_s_barrier();
        __builtin_amdgcn_sched_barrier(0);

        const int sl = kt & 1;
        bf16x8 af[2], bfr[4];
        #pragma unroll
        for (int i = 0; i < 2; i++) af[i]  = *(const bf16x8*)&As[sl][(wr * 32 + i * 16 + lo) * 32 + hi * 8];
        #pragma unroll
        for (int j = 0; j < 4; j++) bfr[j] = *(const bf16x8*)&Bs[sl][(wc * 64 + j * 16 + lo) * 32 + hi * 8];
        #pragma unroll
        for (int i = 0; i < 2; i++)
            #pragma unroll
            for (int j = 0; j < 4; j++)
                acc[i][j] = __builtin_amdgcn_mfma_f32_16x16x32_bf16(af[i], bfr[j], acc[i][j], 0, 0, 0);

        __builtin_amdgcn_s_barrier();         // WAR: protect slot before re-stage
    }
    #undef STAGE_G
}

// ======== 64x128 GEMM body: ring-4 counted-vmcnt (r9-proven, for oproj) =====
__device__ __forceinline__ void gemm64_body(
    const u16* __restrict__ A, const u16* __restrict__ B,
    int m0, int n0, u16 (*As)[2048], u16 (*Bs)[4096], f32x4 acc[2][4])
{
    const int tid  = threadIdx.x;
    const int lane = tid & 63;
    const int wid  = tid >> 6;
    const int wr = wid >> 1, wc = wid & 1;
    const int lo = lane & 15, hi = lane >> 4;

    const f32x4 z = {0.f, 0.f, 0.f, 0.f};
    #pragma unroll
    for (int i = 0; i < 2; i++)
        #pragma unroll
        for (int j = 0; j < 4; j++)
            acc[i][j] = z;

    const int NT = DM / 32;                   // 24 K-steps
    const int rowA = tid >> 2;
    const int colA = (tid & 3) << 3;

    #define STAGE_G(kt_, sl_) do {                                            \
        __builtin_amdgcn_global_load_lds(                                     \
            (gu32_c*)&A[(size_t)(m0 + rowA) * DM + (kt_) * 32 + colA],        \
            (su32*)&As[sl_][wid << 9], 16, 0, 0);                             \
        _Pragma("unroll")                                                     \
        for (int r_ = 0; r_ < 2; ++r_) {                                      \
            const int idx_  = r_ * 256 + tid;                                 \
            const int row_  = idx_ >> 2;                                      \
            const int col_  = (idx_ & 3) << 3;                                \
            const int base_ = (r_ * 256 + wid * 64) * 8;                      \
            __builtin_amdgcn_global_load_lds(                                 \
                (gu32_c*)&B[(size_t)(n0 + row_) * DM + (kt_) * 32 + col_],    \
                (su32*)&Bs[sl_][base_], 16, 0, 0);                            \
        }                                                                     \
    } while (0)

    STAGE_G(0, 0);
    STAGE_G(1, 1);

    for (int kt = 0; kt < NT; ++kt) {
        const int k2 = (kt + 2 < NT) ? kt + 2 : NT - 1;   // clamp: never read
        STAGE_G(k2, (kt + 2) & 3);
        asm volatile("s_waitcnt vmcnt(6)" ::: "memory");
        __builtin_amdgcn_s_barrier();
        __builtin_amdgcn_sched_barrier(0);

        const int sl = kt & 3;
        bf16x8 af[2], bfr[4];
        #pragma unroll
        for (int i = 0; i < 2; i++) af[i]  = *(const bf16x8*)&As[sl][(wr * 32 + i * 16 + lo) * 32 + hi * 8];
        #pragma unroll
        for (int j = 0; j < 4; j++) bfr[j] = *(const bf16x8*)&Bs[sl][(wc * 64 + j * 16 + lo) * 32 + hi * 8];
        #pragma unroll
        for (int i = 0; i < 2; i++)
            #pragma unroll
            for (int j = 0; j < 4; j++)
                acc[i][j] = __builtin_amdgcn_mfma_f32_16x16x32_bf16(af[i], bfr[j], acc[i][j], 0, 0, 0);
    }
    #undef STAGE_G
}

// ======== QKV projection with FUSED RoPE (ring-2 body: 24KB LDS, 5/CU) ======
__global__ __launch_bounds__(256, 2) void gemm_qkv(
    const u16* __restrict__ xb, const u16* __restrict__ wt,
    const float* __restrict__ qb, const float* __restrict__ kb,
    const float* __restrict__ vb, const int* __restrict__ pos,
    u16* __restrict__ Q, u16* __restrict__ K, u16* __restrict__ Vt)
{
    __shared__ __align__(16) u16 As[2][2048];
    __shared__ __align__(16) u16 Bs[2][4096];
    const int id = (blockIdx.x & 7) * 160 + (blockIdx.x >> 3);
    const int m0 = (id / 10) * 64;
    const int n0 = (id % 10) * 128;
    f32x4 acc[2][4];
    gemm64_body2(xb, wt, m0, n0, As, Bs, acc);

    const int tid = threadIdx.x;
    const int lane = tid & 63, wid = tid >> 6;
    const int wr = wid >> 1, wc = wid & 1;
    const int lo = lane & 15, hi = lane >> 4;

    const int seg = n0 + wc * 64;            // wave-uniform, 64-aligned

    if (seg >= 1024) {
        // V: [b,g,d,t], ushort4 stores (4 consecutive t)
        #pragma unroll
        for (int j = 0; j < 4; j++) {
            const int nl = seg - 1024 + j * 16 + lo;
            const float bias = vb[nl];
            const int head = nl >> 6, d = nl & 63;
            #pragma unroll
            for (int i = 0; i < 2; i++) {
                ushort4 vs;
                vs.x = f2bf(acc[i][j][0] + bias);
                vs.y = f2bf(acc[i][j][1] + bias);
                vs.z = f2bf(acc[i][j][2] + bias);
                vs.w = f2bf(acc[i][j][3] + bias);
                const int m = m0 + wr * 32 + i * 16 + hi * 4;
                const int b = m >> 10, t = m & 1023;
                *(ushort4*)&Vt[(((size_t)(b * KVH + head)) * HD + d) * SEQ + t] = vs;
            }
        }
    } else {
        const bool isQ = seg < 768;
        const int  segl = isQ ? seg : seg - 768;
        const int  head = segl >> 6;
        const int  Hcnt = isQ ? NHEAD : KVH;
        u16* outp = isQ ? Q : K;
        float bias[4];
        #pragma unroll
        for (int j = 0; j < 4; j++) {
            const int nl = segl + j * 16 + lo;
            bias[j] = isQ ? qb[nl] * QSCALE : kb[nl];
        }
        const float inv0 = exp2f(-(float)lo * ROPE_C);
        const float inv1 = exp2f(-(float)(16 + lo) * ROPE_C);
        int pmode;                             // pos dtype robustness
        if (pos[1] == 1)                         pmode = 0;
        else if (((const float*)pos)[1] == 1.0f) pmode = 1;
        else                                     pmode = 2;
        const int src0 = (hi << 4) | (lo >> 1);
        const int src1 = src0 | 8;
        const bool odd = (lo & 1) != 0;

        #pragma unroll
        for (int i = 0; i < 2; i++) {
            #pragma unroll
            for (int r = 0; r < 4; r++) {
                const float v0 = acc[i][0][r] + bias[0];
                const float v1 = acc[i][1][r] + bias[1];
                const float v2 = acc[i][2][r] + bias[2];
                const float v3 = acc[i][3][r] + bias[3];
                const float p0e = __shfl(v1, src0), p0o = __shfl(v3, src0);
                const float p1e = __shfl(v1, src1), p1o = __shfl(v3, src1);
                const float p2e = __shfl(v0, src0), p2o = __shfl(v2, src0);
                const float p3e = __shfl(v0, src1), p3o = __shfl(v2, src1);
                const float px0 = odd ? p0o : p0e;
                const float px1 = odd ? p1o : p1e;
                const float px2 = odd ? p2o : p2e;
                const float px3 = odd ? p3o : p3e;

                const int m = m0 + wr * 32 + i * 16 + hi * 4 + r;
                const int b = m >> 10, t = m & 1023;
                float pp;
                if (pmode == 0)      pp = (float)pos[t];
                else if (pmode == 1) pp = ((const float*)pos)[t];
                else                 pp = (float)pos[2 * t];

                const float a0 = pp * inv0, a1 = pp * inv1;
                const float sv0 = __sinf(a0), cv0 = __cosf(a0);
                const float sv1 = __sinf(a1), cv1 = __cosf(a1);
                const float o0 = v0 * cv0 - px0 * sv0;
                const float o1 = v1 * cv1 - px1 * sv1;
                const float o2 = v2 * cv0 + px2 * sv0;
                const float o3 = v3 * cv1 + px3 * sv1;

                u16* dst = outp + ((size_t)(b * Hcnt + head) * SEQ + t) * HD;
                dst[lo]      = f2bf(o0);
                dst[16 + lo] = f2bf(o1);
                dst[32 + lo] = f2bf(o2);
                dst[48 + lo] = f2bf(o3);
            }
        }
    }
}

// ======== output projection: ring-4 body (grid 768 = 3/CU, single batch) ====
__global__ __launch_bounds__(256, 2) void gemm_oproj(
    const u16* __restrict__ Ab, const u16* __restrict__ wt,
    const float* __restrict__ ob, float* __restrict__ outp)
{
    __shared__ __align__(16) u16 As[4][2048];
    __shared__ __align__(16) u16 Bs[4][4096];
    const int id = (blockIdx.x & 7) * 96 + (blockIdx.x >> 3);
    const int m0 = (id / 6) * 64;
    const int n0 = (id % 6) * 128;
    f32x4 acc[2][4];
    gemm64_body(Ab, wt, m0, n0, As, Bs, acc);

    const int tid = threadIdx.x;
    const int lane = tid & 63, wid = tid >> 6;
    const int wr = wid >> 1, wc = wid & 1;
    const int lo = lane & 15, hi = lane >> 4;

    #pragma unroll
    for (int j = 0; j < 4; j++) {
        const int n = n0 + wc * 64 + j * 16 + lo;
        const float bias = ob[n];
        #pragma unroll
        for (int i = 0; i < 2; i++) {
            #pragma unroll
            for (int r = 0; r < 4; r++) {
                const int m = m0 + wr * 32 + i * 16 + hi * 4 + r;
                outp[(size_t)m * DM + n] = acc[i][j][r] + bias;
            }
        }
    }
}

// ======== flash attention v12: ring-3, single leading barrier ===============
// WAR proof (ring-3, depth-1, ONE barrier/iter): between barrier(st-1) and
// barrier(st), LDS activity is laggards reading slot (st-1)%3 and the DMA
// writing slot (st+1)%3 -- difference 2 mod 3 != 0, disjoint.  Own-iteration
// compute(st) reads slot st%3, also != (st+1)%3.  vmcnt(5): leaves STAGE(st+1)
// in flight, drains STAGE(st).  LDS 24KB -> still 6 blocks/CU (144<=160),
// single dispatch batch; barrier count HALVED vs r17's ring-2.
__device__ __forceinline__ void strip_compute(
    const bf16x8& qf0, const bf16x8& qf1,
    const bf16x8& k0, const bf16x8& k1, const bf16x8& k2, const bf16x8& k3,
    const bf16x8* vv, bool diag, int msk0, int hi,
    float& m, float& l, f32x4* O)
{
    const f32x4 z = {0.f, 0.f, 0.f, 0.f};
    f32x4 a0 = z, a1 = z;
    __builtin_amdgcn_s_setprio(1);
    a0 = __builtin_amdgcn_mfma_f32_16x16x32_bf16(k0, qf0, a0, 0, 0, 0);
    a0 = __builtin_amdgcn_mfma_f32_16x16x32_bf16(k1, qf1, a0, 0, 0, 0);
    a1 = __builtin_amdgcn_mfma_f32_16x16x32_bf16(k2, qf0, a1, 0, 0, 0);
    a1 = __builtin_amdgcn_mfma_f32_16x16x32_bf16(k3, qf1, a1, 0, 0, 0);
    __builtin_amdgcn_s_setprio(0);

    float sc[8];
    #pragma unroll
    for (int e = 0; e < 8; ++e)
        sc[e] = (e < 4) ? a0[e & 3] : a1[e & 3];
    if (diag) {
        #pragma unroll
        for (int e = 0; e < 8; ++e) {
            const int srel = ((e >> 2) << 4) + (hi << 2) + (e & 3);
            if (srel > msk0) sc[e] = -3.0e38f;
        }
    }
    float pm = sc[0];
    #pragma unroll
    for (int e = 1; e < 8; ++e) pm = fmaxf(pm, sc[e]);

    if (!__all(pm - m <= 8.0f)) {            // defer-max (per-lane == per-row)
        float pr = fmaxf(pm, __shfl_xor(pm, 16));
        pr = fmaxf(pr, __shfl_xor(pr, 32));
        const float mn = fmaxf(m, pr);
        const float f = exp2f(m - mn);       // first tile: m=-3e38 -> f=0
        l *= f;
        #pragma unroll
        for (int r = 0; r < 4; ++r) {
            const float fr = __shfl(f, hi * 4 + r);
            #pragma unroll
            for (int dj = 0; dj < 4; ++dj) O[dj][r] *= fr;
        }
        m = mn;
    }

    union { u16 u[8]; bf16x8 v; } pu;
    float ps = 0.f;
    #pragma unroll
    for (int e = 0; e < 8; ++e) {
        const float p = exp2f(sc[e] - m);    // bounded by 2^8
        ps += p;
        pu.u[e] = f2bf(p);
    }
    l += ps;                                  // per-lane partial

    __builtin_amdgcn_s_setprio(1);
    #pragma unroll
    for (int dj = 0; dj < 4; ++dj)
        O[dj] = __builtin_amdgcn_mfma_f32_16x16x32_bf16(pu.v, vv[dj], O[dj], 0, 0, 0);
    __builtin_amdgcn_s_setprio(0);
}

__global__ __launch_bounds__(256, 6) void attn_mfma(
    const u16* __restrict__ Q, const u16* __restrict__ K,
    const u16* __restrict__ Vt, u16* __restrict__ outp)
{
    __shared__ __align__(16) u16 Ks[3][2048];   // ring-3: 32 s x 64 d, swizzled
    __shared__ __align__(16) u16 Vs[3][2048];   // ring-3: 64 d x 32 s, permuted

    const int blk = blockIdx.x;                  // 1536 = 8b*12h*16a
    const int xcd = blk & 7;
    const int jj  = blk >> 3;                    // 0..191
    const int bg  = (xcd << 2) + (jj & 3);       // 0..31
    const int rh  = jj >> 2;                     // 0..47
    const int a   = 15 - rh / 3;                 // q-block, DESCENDING (LPT)
    const int hl  = rh % 3;
    const int b   = bg >> 2, g = bg & 3;
    const int h   = g * REP + hl;

    const int wid  = threadIdx.x >> 6;
    const int lane = threadIdx.x & 63;
    const int lo = lane & 15, hi = lane >> 4;

    const int w    = (a << 2) + wid;             // strip 0..63 (16 q-rows)
    const int q0   = w << 4;
    const int dT   = w >> 1;                     // last tile for this strip
    const int msk0 = lo + ((w & 1) << 4);
    const int nstT = (a << 1) + 2;               // block trip count (= max dT+1)

    const u16* Kp = K  + (size_t)(b * KVH + g) * SEQ * HD;
    const u16* Vp = Vt + (size_t)(b * KVH + g) * SEQ * HD;   // [d][s]

    const int jK = (wid << 6) + lane;
    const int sKoff = (jK ^ ((jK >> 3) & 7)) << 3;           // u16 offset
    int vsoff[4];
    #pragma unroll
    for (int q = 0; q < 4; ++q) {
        const int dw  = (wid << 8) + (q << 6) + lane;
        const int R   = dw >> 4;
        const int wd  = dw & 15;
        const int hpl = (wd >> 2) ^ ((R >> 1) & 3);
        vsoff[q] = (R << 10) + (hpl << 2) + (((wd >> 1) & 1) << 4) + ((wd & 1) << 1);
    }

    const u16* Qp = Q + ((size_t)(b * NHEAD + h) * SEQ + q0) * HD;
    const bf16x8 qf0 = *(const bf16x8*)&Qp[(size_t)lo * HD + hi * 8];
    const bf16x8 qf1 = *(const bf16x8*)&Qp[(size_t)lo * HD + 32 + hi * 8];

    const f32x4 z = {0.f, 0.f, 0.f, 0.f};
    f32x4 O[4];
    #pragma unroll
    for (int dj = 0; dj < 4; ++dj) O[dj] = z;
    float m = -3.0e38f, l = 0.f;

    #define STAGE(st_, sl_) do {                                              \
        const int s0_ = (st_) << 5;                                           \
        __builtin_amdgcn_global_load_lds(                                     \
            (gu32_c*)(Kp + (s0_ << 6) + sKoff),                               \
            (su32*)&Ks[sl_][wid << 9], 16, 0, 0);                             \
        _Pragma("unroll")                                                     \
        for (int q_ = 0; q_ < 4; ++q_)                                        \
            __builtin_amdgcn_global_load_lds(                                 \
                (gu32_c*)(Vp + s0_ + vsoff[q_]),                              \
                (su32*)&Vs[sl_][(wid << 9) + (q_ << 7)], 4, 0, 0);            \
    } while (0)

    STAGE(0, 0);

    const int xorK = lo & 7;
    int cur = 0, nxt = 1;                        // rolling slot indices mod 3
    for (int st = 0; st < nstT; ++st) {
        const int s1 = (st + 1 < nstT) ? st + 1 : nstT - 1;  // clamp: never read
        STAGE(s1, nxt);
        asm volatile("s_waitcnt vmcnt(5)" ::: "memory");
        __builtin_amdgcn_s_barrier();
        __builtin_amdgcn_sched_barrier(0);

        if (st <= dT) {
            const u16* kb_ = Ks[cur];
            const bf16x8 k0 = *(const bf16x8*)&kb_[((lo << 3) + (hi ^ xorK)) << 3];
            const bf16x8 k1 = *(const bf16x8*)&kb_[((lo << 3) + ((4 + hi) ^ xorK)) << 3];
            const bf16x8 k2 = *(const bf16x8*)&kb_[(((16 + lo) << 3) + (hi ^ xorK)) << 3];
            const bf16x8 k3 = *(const bf16x8*)&kb_[(((16 + lo) << 3) + ((4 + hi) ^ xorK)) << 3];
            bf16x8 vv[4];
            #pragma unroll
            for (int dj = 0; dj < 4; ++dj) {
                const int R = dj * 16 + lo;
                vv[dj] = *(const bf16x8*)&Vs[cur][(R << 5) + ((hi ^ ((R >> 1) & 3)) << 3)];
            }
            strip_compute(qf0, qf1, k0, k1, k2, k3, vv, st == dT, msk0, hi, m, l, O);
        }
        cur = (cur == 2) ? 0 : cur + 1;
        nxt = (nxt == 2) ? 0 : nxt + 1;
    }
    #undef STAGE

    // epilogue: reduce per-lane l across hi-groups, then per-row store
    l += __shfl_xor(l, 16); l += __shfl_xor(l, 32);
    #pragma unroll
    for (int r = 0; r < 4; ++r) {
        const float li = 1.0f / fmaxf(__shfl(l, hi * 4 + r), 1e-37f);
        const int t = q0 + hi * 4 + r;
        #pragma unroll
        for (int dj = 0; dj < 4; ++dj)
            outp[((size_t)(b * SEQ + t)) * DM + h * HD + dj * 16 + lo] = f2bf(O[dj][r] * li);
    }
}

extern "C" void kernel_launch(void* const* d_in, const int* in_sizes, int n_in,
                              void* d_out, int out_size, void* d_ws, size_t ws_size,
                              hipStream_t stream) {
    const float* x   = (const float*)d_in[0];
    const int*   pos = (const int*)d_in[1];
    const float* qw  = (const float*)d_in[2];
    const float* qb  = (const float*)d_in[3];
    const float* kw  = (const float*)d_in[4];
    const float* kb  = (const float*)d_in[5];
    const float* vw  = (const float*)d_in[6];
    const float* vb  = (const float*)d_in[7];
    const float* ow  = (const float*)d_in[8];
    const float* ob  = (const float*)d_in[9];
    float* out = (float*)d_out;                 // OUTPUT IS FP32

    u16* xb    = (u16*)d_ws;                                    // 6291456
    u16* Wqkvt = xb    + (size_t)8192 * DM;                     //  983040
    u16* Wot   = Wqkvt + (size_t)1280 * DM;                     //  589824
    u16* Qbuf  = Wot   + (size_t)DM * DM;                       // 6291456 (rope'd)
    u16* Kbuf  = Qbuf  + (size_t)BATCH * NHEAD * SEQ * HD;      // 2097152 (rope'd)
    u16* Vtb   = Kbuf  + (size_t)BATCH * KVH * SEQ * HD;        // 2097152 [b,g,d,s]
    u16* attn  = xb;     // alias: xb dead after gemm_qkv

    const int NCVT = 8192 * DM / 4 + 1280 * DM + DM * DM;
    cvt_all<<<(NCVT + 255) / 256, 256, 0, stream>>>(x, qw, kw, vw, ow, xb, Wqkvt, Wot);

    gemm_qkv<<<1280, 256, 0, stream>>>(xb, Wqkvt, qb, kb, vb, pos, Qbuf, Kbuf, Vtb);

    attn_mfma<<<1536, 256, 0, stream>>>(Qbuf, Kbuf, Vtb, attn);

    gemm_oproj<<<768, 256, 0, stream>>>(attn, Wot, ob, out);
}